// Round 1
// baseline (2087.732 us; speedup 1.0000x reference)
//
#include <hip/hip_runtime.h>

#define BLK 256

// ---------------- degree / count: atomicAdd 1.0 per edge at dst ----------------
__global__ void k_deg(const int* __restrict__ dst, float* __restrict__ deg, int E) {
    int e = blockIdx.x * blockDim.x + threadIdx.x;
    if (e < E) atomicAdd(&deg[dst[e]], 1.0f);
}

// in-place deg -> (deg>0 ? rsqrt(deg) : 0)
__global__ void k_dinv(float* __restrict__ deg, int n) {
    int i = blockIdx.x * blockDim.x + threadIdx.x;
    if (i < n) { float d = deg[i]; deg[i] = d > 0.f ? rsqrtf(d) : 0.f; }
}

// ---------------- 5-channel normalized scatter (TAGConv1 propagation) ----------------
__global__ void k_scatter5(const float* __restrict__ x, const int* __restrict__ src,
                           const int* __restrict__ dst, const float* __restrict__ dinv,
                           float* __restrict__ out, int E) {
    int e = blockIdx.x * blockDim.x + threadIdx.x;
    if (e >= E) return;
    int s = src[e], d = dst[e];
    float nrm = dinv[s] * dinv[d];
    #pragma unroll
    for (int k = 0; k < 5; k++)
        atomicAdd(&out[d * 5 + k], x[s * 5 + k] * nrm);
}

// ---------------- 64-channel scatter: 64 threads per edge ----------------
// ew: optional per-edge weight; dinv: optional symmetric gcn norm
__global__ void k_scatter64(const float* __restrict__ x, const int* __restrict__ src,
                            const int* __restrict__ dst, const float* __restrict__ ew,
                            const float* __restrict__ dinv,
                            float* __restrict__ out, long long E) {
    long long t = (long long)blockIdx.x * blockDim.x + threadIdx.x;
    if (t >= E * 64) return;
    int e = (int)(t >> 6);
    int j = (int)(t & 63);
    int s = src[e], d = dst[e];
    float v = x[(long long)s * 64 + j];
    if (ew)   v *= ew[e];
    if (dinv) v *= dinv[s] * dinv[d];
    atomicAdd(&out[(long long)d * 64 + j], v);
}

// ---------------- TAGConv1 combine: gx = relu(b + x@W0 + h1@W1 + h2@W2) ----------------
// x,h1,h2: [n,5], W: [3,5,64]
__global__ void k_tag1(const float* __restrict__ x, const float* __restrict__ h1,
                       const float* __restrict__ h2, const float* __restrict__ W,
                       const float* __restrict__ b, float* __restrict__ gx, int n) {
    int t = blockIdx.x * blockDim.x + threadIdx.x;
    if (t >= n * 64) return;
    int i = t >> 6, j = t & 63;
    float acc = b[j];
    #pragma unroll
    for (int k = 0; k < 5; k++) {
        acc += x [i * 5 + k] * W[        k * 64 + j];
        acc += h1[i * 5 + k] * W[320 +   k * 64 + j];
        acc += h2[i * 5 + k] * W[640 +   k * 64 + j];
    }
    gx[t] = fmaxf(acc, 0.f);
}

// ---------------- GraphConv combine: sx = relu(gc_b + agg@W_rel + state_x@W_root) ----------------
__global__ void k_gc(const float* __restrict__ agg, const float* __restrict__ sxin,
                     const float* __restrict__ Wrel, const float* __restrict__ Wroot,
                     const float* __restrict__ b, float* __restrict__ out, int n) {
    int t = blockIdx.x * blockDim.x + threadIdx.x;
    if (t >= n * 64) return;
    int i = t >> 6, j = t & 63;
    float acc = b[j];
    #pragma unroll 8
    for (int k = 0; k < 64; k++) acc += agg[i * 64 + k] * Wrel[k * 64 + j];
    #pragma unroll
    for (int k = 0; k < 6;  k++) acc += sxin[i * 6 + k] * Wroot[k * 64 + j];
    out[t] = fmaxf(acc, 0.f);
}

// ---------------- SAGE combine: sx2 = relu(b_l + (ssum/cnt)@W_l + sx@W_r) ----------------
__global__ void k_sage(const float* __restrict__ ssum, const float* __restrict__ cnt,
                       const float* __restrict__ sx, const float* __restrict__ Wl,
                       const float* __restrict__ Wr, const float* __restrict__ bl,
                       float* __restrict__ out, int n) {
    int t = blockIdx.x * blockDim.x + threadIdx.x;
    if (t >= n * 64) return;
    int i = t >> 6, j = t & 63;
    float r = 1.f / fmaxf(cnt[i], 1.f);
    float acc = bl[j];
    #pragma unroll 8
    for (int k = 0; k < 64; k++) {
        acc += (ssum[i * 64 + k] * r) * Wl[k * 64 + j];
        acc += sx[i * 64 + k] * Wr[k * 64 + j];
    }
    out[t] = fmaxf(acc, 0.f);
}

// ---------------- TAGConv2 combine: sx3 = relu(b + x@W0 + h1@W1 + h2@W2 + h3@W3) ----------------
// W: [4,64,64]
__global__ void k_tag2(const float* __restrict__ x, const float* __restrict__ h1,
                       const float* __restrict__ h2, const float* __restrict__ h3,
                       const float* __restrict__ W, const float* __restrict__ b,
                       float* __restrict__ out, int n) {
    int t = blockIdx.x * blockDim.x + threadIdx.x;
    if (t >= n * 64) return;
    int i = t >> 6, j = t & 63;
    float acc = b[j];
    #pragma unroll 4
    for (int k = 0; k < 64; k++) {
        acc += x [i * 64 + k] * W[         k * 64 + j];
        acc += h1[i * 64 + k] * W[ 4096 +  k * 64 + j];
        acc += h2[i * 64 + k] * W[ 8192 +  k * 64 + j];
        acc += h3[i * 64 + k] * W[12288 +  k * 64 + j];
    }
    out[t] = fmaxf(acc, 0.f);
}

// ---------------- final linear: out = sx3 @ lin_W + lin_b ----------------
__global__ void k_final(const float* __restrict__ x, const float* __restrict__ W,
                        const float* __restrict__ b, float* __restrict__ out, int n) {
    int t = blockIdx.x * blockDim.x + threadIdx.x;
    if (t >= n * 8) return;
    int i = t >> 3, o = t & 7;
    float acc = b[o];
    #pragma unroll 8
    for (int k = 0; k < 64; k++) acc += x[i * 64 + k] * W[k * 8 + o];
    out[t] = acc;
}

static inline unsigned gblk(long long n) { return (unsigned)((n + BLK - 1) / BLK); }

extern "C" void kernel_launch(void* const* d_in, const int* in_sizes, int n_in,
                              void* d_out, int out_size, void* d_ws, size_t ws_size,
                              hipStream_t stream) {
    const float* game_x  = (const float*)d_in[0];
    const float* state_x = (const float*)d_in[1];
    const int*   ei_vv   = (const int*)d_in[2];
    const int*   ei_h    = (const int*)d_in[3];
    const float* ea_h    = (const float*)d_in[4];
    const int*   ei_in   = (const int*)d_in[5];
    const int*   ei_ss   = (const int*)d_in[6];
    const float* tag1_W  = (const float*)d_in[7];
    const float* tag1_b  = (const float*)d_in[8];
    const float* tag2_W  = (const float*)d_in[9];
    const float* tag2_b  = (const float*)d_in[10];
    const float* gc_Wrel = (const float*)d_in[11];
    const float* gc_b    = (const float*)d_in[12];
    const float* gc_Wroot= (const float*)d_in[13];
    const float* sage_Wl = (const float*)d_in[14];
    const float* sage_bl = (const float*)d_in[15];
    const float* sage_Wr = (const float*)d_in[16];
    const float* lin_W   = (const float*)d_in[17];
    const float* lin_b   = (const float*)d_in[18];

    const int NV  = in_sizes[0] / 5;
    const int NS  = in_sizes[1] / 6;
    const int EVV = in_sizes[2] / 2;
    const int EH  = in_sizes[3] / 2;
    const int EIN = in_sizes[5] / 2;
    const int ESS = in_sizes[6] / 2;

    const int *vv_s = ei_vv,  *vv_d = ei_vv + EVV;
    const int *h_s  = ei_h,   *h_d  = ei_h  + EH;
    const int *in_s = ei_in,  *in_d = ei_in + EIN;
    const int *ss_s = ei_ss,  *ss_d = ei_ss + ESS;

    // -------- workspace layout (floats) --------
    float* ws = (float*)d_ws;
    size_t o = 0;
    float* dinv_v = ws + o; o += (size_t)NV;
    float* h1v    = ws + o; o += (size_t)NV * 5;
    float* h2v    = ws + o; o += (size_t)NV * 5;
    float* gx     = ws + o; o += (size_t)NV * 64;   // later reused as sx3
    float* agg    = ws + o; o += (size_t)NS * 64;   // later reused as hs1
    float* ssum   = ws + o; o += (size_t)NS * 64;   // later reused as hs2
    float* sxb    = ws + o; o += (size_t)NS * 64;   // sx, later reused as hs3
    float* sx2    = ws + o; o += (size_t)NS * 64;
    float* cnt    = ws + o; o += (size_t)NS;
    float* dinv_s = ws + o; o += (size_t)NS;
    float* sx3    = gx;

    // ================= Stage A: TAGConv1 on v-v graph (propagate in 5-dim space) ====
    hipMemsetAsync(dinv_v, 0, (size_t)NV * sizeof(float), stream);
    k_deg <<<gblk(EVV), BLK, 0, stream>>>(vv_d, dinv_v, EVV);
    k_dinv<<<gblk(NV),  BLK, 0, stream>>>(dinv_v, NV);
    hipMemsetAsync(h1v, 0, (size_t)NV * 10 * sizeof(float), stream);  // h1v+h2v contiguous
    k_scatter5<<<gblk(EVV), BLK, 0, stream>>>(game_x, vv_s, vv_d, dinv_v, h1v, EVV);
    k_scatter5<<<gblk(EVV), BLK, 0, stream>>>(h1v,    vv_s, vv_d, dinv_v, h2v, EVV);
    k_tag1<<<gblk((long long)NV * 64), BLK, 0, stream>>>(game_x, h1v, h2v, tag1_W, tag1_b, gx, NV);

    // ================= Stage B: GraphConv (weighted sum over history edges) =========
    hipMemsetAsync(agg, 0, (size_t)NS * 64 * sizeof(float), stream);
    k_scatter64<<<gblk((long long)EH * 64), BLK, 0, stream>>>(gx, h_s, h_d, ea_h, nullptr, agg, EH);
    k_gc<<<gblk((long long)NS * 64), BLK, 0, stream>>>(agg, state_x, gc_Wrel, gc_Wroot, gc_b, sxb, NS);

    // ================= Stage C: SAGE mean over in edges =============================
    hipMemsetAsync(ssum, 0, (size_t)NS * 64 * sizeof(float), stream);
    hipMemsetAsync(cnt,  0, (size_t)NS * sizeof(float), stream);
    k_scatter64<<<gblk((long long)EIN * 64), BLK, 0, stream>>>(gx, in_s, in_d, nullptr, nullptr, ssum, EIN);
    k_deg<<<gblk(EIN), BLK, 0, stream>>>(in_d, cnt, EIN);
    k_sage<<<gblk((long long)NS * 64), BLK, 0, stream>>>(ssum, cnt, sxb, sage_Wl, sage_Wr, sage_bl, sx2, NS);

    // ================= Stage D: TAGConv2 on s-s graph (64-dim, K=3) =================
    hipMemsetAsync(dinv_s, 0, (size_t)NS * sizeof(float), stream);
    k_deg <<<gblk(ESS), BLK, 0, stream>>>(ss_d, dinv_s, ESS);
    k_dinv<<<gblk(NS),  BLK, 0, stream>>>(dinv_s, NS);

    float* hs1 = agg;   // dead buffers reused
    float* hs2 = ssum;
    float* hs3 = sxb;
    hipMemsetAsync(hs1, 0, (size_t)NS * 64 * sizeof(float), stream);
    k_scatter64<<<gblk((long long)ESS * 64), BLK, 0, stream>>>(sx2, ss_s, ss_d, nullptr, dinv_s, hs1, ESS);
    hipMemsetAsync(hs2, 0, (size_t)NS * 64 * sizeof(float), stream);
    k_scatter64<<<gblk((long long)ESS * 64), BLK, 0, stream>>>(hs1, ss_s, ss_d, nullptr, dinv_s, hs2, ESS);
    hipMemsetAsync(hs3, 0, (size_t)NS * 64 * sizeof(float), stream);
    k_scatter64<<<gblk((long long)ESS * 64), BLK, 0, stream>>>(hs2, ss_s, ss_d, nullptr, dinv_s, hs3, ESS);
    k_tag2<<<gblk((long long)NS * 64), BLK, 0, stream>>>(sx2, hs1, hs2, hs3, tag2_W, tag2_b, sx3, NS);

    // ================= Stage E: final linear ========================================
    k_final<<<gblk((long long)NS * 8), BLK, 0, stream>>>(sx3, lin_W, lin_b, (float*)d_out, NS);
}

// Round 2
// 1413.735 us; speedup vs baseline: 1.4767x; 1.4767x over previous
//
#include <hip/hip_runtime.h>

#define BLK 256

// ================= CSR construction =================

__global__ void k_hist(const int* __restrict__ dst, int* __restrict__ deg, int E) {
    int e = blockIdx.x * blockDim.x + threadIdx.x;
    if (e < E) atomicAdd(&deg[dst[e]], 1);
}

// per-256-block exclusive scan; block sums out
__global__ void k_scan_block(const int* __restrict__ deg, int* __restrict__ excl,
                             int* __restrict__ bsum, int n) {
    __shared__ int sh[256];
    int i = blockIdx.x * 256 + threadIdx.x;
    int v = (i < n) ? deg[i] : 0;
    sh[threadIdx.x] = v; __syncthreads();
    for (int off = 1; off < 256; off <<= 1) {
        int t = (threadIdx.x >= (unsigned)off) ? sh[threadIdx.x - off] : 0;
        __syncthreads();
        sh[threadIdx.x] += t; __syncthreads();
    }
    if (i < n) excl[i] = sh[threadIdx.x] - v;
    if (threadIdx.x == 255) bsum[blockIdx.x] = sh[255];
}

// single-block exclusive scan of up to 1024 block sums, in place
__global__ void k_scan_top(int* __restrict__ bsum, int nb) {
    __shared__ int sh[1024];
    int tid = threadIdx.x;
    int v = (tid < nb) ? bsum[tid] : 0;
    sh[tid] = v; __syncthreads();
    for (int off = 1; off < 1024; off <<= 1) {
        int t = (tid >= off) ? sh[tid - off] : 0;
        __syncthreads();
        sh[tid] += t; __syncthreads();
    }
    if (tid < nb) bsum[tid] = sh[tid] - v;
}

// finalize rowptr, init cursor copy, set rowptr[n]=E
__global__ void k_scan_add(int* __restrict__ rowptr, const int* __restrict__ bsum,
                           int* __restrict__ cursor, int n, int E) {
    int i = blockIdx.x * blockDim.x + threadIdx.x;
    if (i < n) { int r = rowptr[i] + bsum[i >> 8]; rowptr[i] = r; cursor[i] = r; }
    if (i == 0) rowptr[n] = E;
}

__global__ void k_fill(const int* __restrict__ src, const int* __restrict__ dst,
                       int* __restrict__ cursor, int* __restrict__ csr_src, int E) {
    int e = blockIdx.x * blockDim.x + threadIdx.x;
    if (e >= E) return;
    int p = atomicAdd(&cursor[dst[e]], 1);
    csr_src[p] = src[e];
}

__global__ void k_fill_w(const int* __restrict__ src, const int* __restrict__ dst,
                         const float* __restrict__ w, int* __restrict__ cursor,
                         int* __restrict__ csr_src, float* __restrict__ csr_w, int E) {
    int e = blockIdx.x * blockDim.x + threadIdx.x;
    if (e >= E) return;
    int p = atomicAdd(&cursor[dst[e]], 1);
    csr_src[p] = src[e];
    csr_w[p] = w[e];
}

// dinv[i] = deg>0 ? rsqrt(deg) : 0, deg from rowptr diff
__global__ void k_dinv_rp(const int* __restrict__ rowptr, float* __restrict__ dinv, int n) {
    int i = blockIdx.x * blockDim.x + threadIdx.x;
    if (i < n) { int d = rowptr[i + 1] - rowptr[i]; dinv[i] = d > 0 ? rsqrtf((float)d) : 0.f; }
}

// ================= gathers =================

// 5-channel gcn-normalized gather: one thread per dst node
__global__ void k_gather5(const float* __restrict__ x, const int* __restrict__ rowptr,
                          const int* __restrict__ csr_src, const float* __restrict__ dinv,
                          float* __restrict__ out, int n) {
    int d = blockIdx.x * blockDim.x + threadIdx.x;
    if (d >= n) return;
    int b = rowptr[d], e = rowptr[d + 1];
    float dd = dinv[d];
    float a0 = 0, a1 = 0, a2 = 0, a3 = 0, a4 = 0;
    for (int p = b; p < e; p++) {
        int s = csr_src[p];
        float w = dd * dinv[s];
        const float* xp = x + (size_t)s * 5;
        a0 += xp[0] * w; a1 += xp[1] * w; a2 += xp[2] * w; a3 += xp[3] * w; a4 += xp[4] * w;
    }
    float* op = out + (size_t)d * 5;
    op[0] = a0; op[1] = a1; op[2] = a2; op[3] = a3; op[4] = a4;
}

// 64-channel gather: one wave (64 lanes) per dst node, lane = channel
__global__ void k_gather64(const float* __restrict__ x, const int* __restrict__ rowptr,
                           const int* __restrict__ csr_src, const float* __restrict__ csr_w,
                           const float* __restrict__ dinv, float* __restrict__ out, int n) {
    int t = blockIdx.x * blockDim.x + threadIdx.x;
    int d = t >> 6, j = t & 63;
    if (d >= n) return;
    int b = rowptr[d], e = rowptr[d + 1];
    float dd = dinv ? dinv[d] : 0.f;
    float acc = 0.f;
    for (int p = b; p < e; p++) {
        int s = csr_src[p];
        float v = x[(size_t)s * 64 + j];
        if (csr_w) v *= csr_w[p];
        if (dinv)  v *= dd * dinv[s];
        acc += v;
    }
    out[(size_t)d * 64 + j] = acc;
}

// ================= dense combines =================

// gx = relu(b + x@W0 + h1@W1 + h2@W2), x,h1,h2:[n,5], W:[3,5,64]
__global__ void k_tag1(const float* __restrict__ x, const float* __restrict__ h1,
                       const float* __restrict__ h2, const float* __restrict__ W,
                       const float* __restrict__ b, float* __restrict__ gx, int n) {
    int t = blockIdx.x * blockDim.x + threadIdx.x;
    if (t >= n * 64) return;
    int i = t >> 6, j = t & 63;
    float acc = b[j];
    #pragma unroll
    for (int k = 0; k < 5; k++) {
        acc += x [i * 5 + k] * W[      k * 64 + j];
        acc += h1[i * 5 + k] * W[320 + k * 64 + j];
        acc += h2[i * 5 + k] * W[640 + k * 64 + j];
    }
    gx[t] = fmaxf(acc, 0.f);
}

// sx = relu(gc_b + agg@W_rel + state_x@W_root)
__global__ void k_gc(const float* __restrict__ agg, const float* __restrict__ sxin,
                     const float* __restrict__ Wrel, const float* __restrict__ Wroot,
                     const float* __restrict__ b, float* __restrict__ out, int n) {
    int t = blockIdx.x * blockDim.x + threadIdx.x;
    if (t >= n * 64) return;
    int i = t >> 6, j = t & 63;
    float acc = b[j];
    #pragma unroll 8
    for (int k = 0; k < 64; k++) acc += agg[i * 64 + k] * Wrel[k * 64 + j];
    #pragma unroll
    for (int k = 0; k < 6;  k++) acc += sxin[i * 6 + k] * Wroot[k * 64 + j];
    out[t] = fmaxf(acc, 0.f);
}

// sx2 = relu(b_l + (ssum/max(cnt,1))@W_l + sx@W_r); cnt from rowptr diff
__global__ void k_sage(const float* __restrict__ ssum, const int* __restrict__ rowptr_in,
                       const float* __restrict__ sx, const float* __restrict__ Wl,
                       const float* __restrict__ Wr, const float* __restrict__ bl,
                       float* __restrict__ out, int n) {
    int t = blockIdx.x * blockDim.x + threadIdx.x;
    if (t >= n * 64) return;
    int i = t >> 6, j = t & 63;
    float cnt = (float)(rowptr_in[i + 1] - rowptr_in[i]);
    float r = 1.f / fmaxf(cnt, 1.f);
    float acc = bl[j];
    #pragma unroll 8
    for (int k = 0; k < 64; k++) {
        acc += (ssum[i * 64 + k] * r) * Wl[k * 64 + j];
        acc += sx[i * 64 + k] * Wr[k * 64 + j];
    }
    out[t] = fmaxf(acc, 0.f);
}

// out = b + x@W   (W 64x64)
__global__ void k_mm_init(const float* __restrict__ x, const float* __restrict__ W,
                          const float* __restrict__ b, float* __restrict__ out, int n) {
    int t = blockIdx.x * blockDim.x + threadIdx.x;
    if (t >= n * 64) return;
    int i = t >> 6, j = t & 63;
    float acc = b[j];
    #pragma unroll 8
    for (int k = 0; k < 64; k++) acc += x[i * 64 + k] * W[k * 64 + j];
    out[t] = acc;
}

// out += h@W
__global__ void k_mm_acc(const float* __restrict__ h, const float* __restrict__ W,
                         float* __restrict__ out, int n) {
    int t = blockIdx.x * blockDim.x + threadIdx.x;
    if (t >= n * 64) return;
    int i = t >> 6, j = t & 63;
    float acc = 0.f;
    #pragma unroll 8
    for (int k = 0; k < 64; k++) acc += h[i * 64 + k] * W[k * 64 + j];
    out[t] += acc;
}

// out = relu(sx3) @ lin_W + lin_b
__global__ void k_final(const float* __restrict__ x, const float* __restrict__ W,
                        const float* __restrict__ b, float* __restrict__ out, int n) {
    int t = blockIdx.x * blockDim.x + threadIdx.x;
    if (t >= n * 8) return;
    int i = t >> 3, o = t & 7;
    float acc = b[o];
    #pragma unroll 8
    for (int k = 0; k < 64; k++) acc += fmaxf(x[i * 64 + k], 0.f) * W[k * 8 + o];
    out[t] = acc;
}

static inline unsigned gblk(long long n) { return (unsigned)((n + BLK - 1) / BLK); }

// host-side helper: build CSR for (dst,E,N) into rowptr/cursor/(fill later)
static void build_csr_base(const int* dst, int E, int N,
                           int* rowptr, int* cursor, int* bsum, hipStream_t stream) {
    hipMemsetAsync(cursor, 0, (size_t)N * sizeof(int), stream);
    k_hist<<<gblk(E), BLK, 0, stream>>>(dst, cursor, E);
    int nb = (N + 255) / 256;
    k_scan_block<<<nb, 256, 0, stream>>>(cursor, rowptr, bsum, N);
    k_scan_top<<<1, 1024, 0, stream>>>(bsum, nb);
    k_scan_add<<<gblk(N), BLK, 0, stream>>>(rowptr, bsum, cursor, N, E);
}

extern "C" void kernel_launch(void* const* d_in, const int* in_sizes, int n_in,
                              void* d_out, int out_size, void* d_ws, size_t ws_size,
                              hipStream_t stream) {
    const float* game_x  = (const float*)d_in[0];
    const float* state_x = (const float*)d_in[1];
    const int*   ei_vv   = (const int*)d_in[2];
    const int*   ei_h    = (const int*)d_in[3];
    const float* ea_h    = (const float*)d_in[4];
    const int*   ei_in   = (const int*)d_in[5];
    const int*   ei_ss   = (const int*)d_in[6];
    const float* tag1_W  = (const float*)d_in[7];
    const float* tag1_b  = (const float*)d_in[8];
    const float* tag2_W  = (const float*)d_in[9];
    const float* tag2_b  = (const float*)d_in[10];
    const float* gc_Wrel = (const float*)d_in[11];
    const float* gc_b    = (const float*)d_in[12];
    const float* gc_Wroot= (const float*)d_in[13];
    const float* sage_Wl = (const float*)d_in[14];
    const float* sage_bl = (const float*)d_in[15];
    const float* sage_Wr = (const float*)d_in[16];
    const float* lin_W   = (const float*)d_in[17];
    const float* lin_b   = (const float*)d_in[18];

    const int NV  = in_sizes[0] / 5;
    const int NS  = in_sizes[1] / 6;
    const int EVV = in_sizes[2] / 2;
    const int EH  = in_sizes[3] / 2;
    const int EIN = in_sizes[5] / 2;
    const int ESS = in_sizes[6] / 2;

    const int *vv_s = ei_vv,  *vv_d = ei_vv + EVV;
    const int *h_s  = ei_h,   *h_d  = ei_h  + EH;
    const int *in_s = ei_in,  *in_d = ei_in + EIN;
    const int *ss_s = ei_ss,  *ss_d = ei_ss + ESS;

    // ---------------- workspace layout (4-byte words) ----------------
    float* wsf = (float*)d_ws;
    size_t o = 0;
    float* gx   = wsf + o; o += (size_t)NV * 64;                        // sx3 reuses this
    float* B1   = wsf + o; o += (size_t)NS * 64 + ((size_t)NS * 2 + (size_t)EIN + 64); // agg | (inCSR+ssum) | hA
    float* B2   = wsf + o; o += (size_t)NS * 64;                        // sx | hB
    float* B4   = wsf + o; o += (size_t)NS * 64;                        // h1v+h2v | hCSR | sx2
    float* pool = wsf + o; o += (size_t)NV + (size_t)NV + (size_t)EVV + 64; // vv CSR | ss CSR
    float* dinv = wsf + o; o += (size_t)NV;                             // dinv_v | dinv_s
    int*   bsum = (int*)(wsf + o); o += 1024;

    // ================= Stage A: TAGConv1 on v-v =================
    int* vvrp  = (int*)pool;
    int* vvcur = vvrp + NV + 1;
    int* vvsrc = vvcur + NV;
    build_csr_base(vv_d, EVV, NV, vvrp, vvcur, bsum, stream);
    k_dinv_rp<<<gblk(NV), BLK, 0, stream>>>(vvrp, dinv, NV);
    k_fill<<<gblk(EVV), BLK, 0, stream>>>(vv_s, vv_d, vvcur, vvsrc, EVV);

    float* h1v = B4;
    float* h2v = B4 + (size_t)NV * 5;
    k_gather5<<<gblk(NV), BLK, 0, stream>>>(game_x, vvrp, vvsrc, dinv, h1v, NV);
    k_gather5<<<gblk(NV), BLK, 0, stream>>>(h1v,    vvrp, vvsrc, dinv, h2v, NV);
    k_tag1<<<gblk((long long)NV * 64), BLK, 0, stream>>>(game_x, h1v, h2v, tag1_W, tag1_b, gx, NV);

    // ================= Stage B: GraphConv (weighted) =================
    int*   hrp  = (int*)B4;                 // h1v/h2v dead
    int*   hcur = hrp + NS + 1;
    int*   hsrc = hcur + NS;
    float* hw   = (float*)(hsrc + EH);
    build_csr_base(h_d, EH, NS, hrp, hcur, bsum, stream);
    k_fill_w<<<gblk(EH), BLK, 0, stream>>>(h_s, h_d, ea_h, hcur, hsrc, hw, EH);

    float* agg = B1;
    float* sx  = B2;
    k_gather64<<<gblk((long long)NS * 64), BLK, 0, stream>>>(gx, hrp, hsrc, hw, nullptr, agg, NS);
    k_gc<<<gblk((long long)NS * 64), BLK, 0, stream>>>(agg, state_x, gc_Wrel, gc_Wroot, gc_b, sx, NS);

    // ================= Stage C: SAGE mean =================
    int*   inrp  = (int*)B1;                // agg dead
    int*   incur = inrp + NS + 1;
    int*   insrc = incur + NS;
    float* ssum  = B1 + ((size_t)NS * 2 + (size_t)EIN + 32);
    build_csr_base(in_d, EIN, NS, inrp, incur, bsum, stream);
    k_fill<<<gblk(EIN), BLK, 0, stream>>>(in_s, in_d, incur, insrc, EIN);
    k_gather64<<<gblk((long long)NS * 64), BLK, 0, stream>>>(gx, inrp, insrc, nullptr, nullptr, ssum, NS);

    float* sx2 = B4;                        // h CSR dead
    k_sage<<<gblk((long long)NS * 64), BLK, 0, stream>>>(ssum, inrp, sx, sage_Wl, sage_Wr, sage_bl, sx2, NS);

    // ================= Stage D: TAGConv2 on s-s (K=3) =================
    int* ssrp  = (int*)pool;                // vv CSR dead
    int* sscur = ssrp + NS + 1;
    int* sssrc = sscur + NS;
    build_csr_base(ss_d, ESS, NS, ssrp, sscur, bsum, stream);
    k_dinv_rp<<<gblk(NS), BLK, 0, stream>>>(ssrp, dinv, NS);   // dinv_v dead
    k_fill<<<gblk(ESS), BLK, 0, stream>>>(ss_s, ss_d, sscur, sssrc, ESS);

    float* sx3 = gx;                        // gx dead after stage C gather
    float* hA  = B1;                        // in CSR + ssum dead
    float* hB  = B2;                        // sx dead

    k_mm_init<<<gblk((long long)NS * 64), BLK, 0, stream>>>(sx2, tag2_W, tag2_b, sx3, NS);
    k_gather64<<<gblk((long long)NS * 64), BLK, 0, stream>>>(sx2, ssrp, sssrc, nullptr, dinv, hA, NS);
    k_mm_acc<<<gblk((long long)NS * 64), BLK, 0, stream>>>(hA, tag2_W + 4096, sx3, NS);
    k_gather64<<<gblk((long long)NS * 64), BLK, 0, stream>>>(hA, ssrp, sssrc, nullptr, dinv, hB, NS);
    k_mm_acc<<<gblk((long long)NS * 64), BLK, 0, stream>>>(hB, tag2_W + 8192, sx3, NS);
    k_gather64<<<gblk((long long)NS * 64), BLK, 0, stream>>>(hB, ssrp, sssrc, nullptr, dinv, hA, NS);
    k_mm_acc<<<gblk((long long)NS * 64), BLK, 0, stream>>>(hA, tag2_W + 12288, sx3, NS);

    // ================= Stage E: final linear (relu fused) =================
    k_final<<<gblk((long long)NS * 8), BLK, 0, stream>>>(sx3, lin_W, lin_b, (float*)d_out, NS);
}

// Round 3
// 1104.963 us; speedup vs baseline: 1.8894x; 1.2794x over previous
//
#include <hip/hip_runtime.h>

#define BLK 256

// ================= CSR construction =================

__global__ void k_hist(const int* __restrict__ dst, int* __restrict__ deg, int E) {
    int e = blockIdx.x * blockDim.x + threadIdx.x;
    if (e < E) atomicAdd(&deg[dst[e]], 1);
}

// per-256-block exclusive scan; block sums out; optional dinv = rsqrt(deg)
__global__ void k_scan_block(const int* __restrict__ deg, int* __restrict__ excl,
                             int* __restrict__ bsum, float* __restrict__ dinv, int n) {
    __shared__ int sh[256];
    int i = blockIdx.x * 256 + threadIdx.x;
    int v = (i < n) ? deg[i] : 0;
    if (dinv && i < n) dinv[i] = v > 0 ? rsqrtf((float)v) : 0.f;
    sh[threadIdx.x] = v; __syncthreads();
    for (int off = 1; off < 256; off <<= 1) {
        int t = (threadIdx.x >= (unsigned)off) ? sh[threadIdx.x - off] : 0;
        __syncthreads();
        sh[threadIdx.x] += t; __syncthreads();
    }
    if (i < n) excl[i] = sh[threadIdx.x] - v;
    if (threadIdx.x == 255) bsum[blockIdx.x] = sh[255];
}

// single-block exclusive scan of up to 1024 block sums, in place
__global__ void k_scan_top(int* __restrict__ bsum, int nb) {
    __shared__ int sh[1024];
    int tid = threadIdx.x;
    int v = (tid < nb) ? bsum[tid] : 0;
    sh[tid] = v; __syncthreads();
    for (int off = 1; off < 1024; off <<= 1) {
        int t = (tid >= off) ? sh[tid - off] : 0;
        __syncthreads();
        sh[tid] += t; __syncthreads();
    }
    if (tid < nb) bsum[tid] = sh[tid] - v;
}

// finalize rowptr, init cursor copy, set rowptr[n]=E
__global__ void k_scan_add(int* __restrict__ rowptr, const int* __restrict__ bsum,
                           int* __restrict__ cursor, int n, int E) {
    int i = blockIdx.x * blockDim.x + threadIdx.x;
    if (i < n) { int r = rowptr[i] + bsum[i >> 8]; rowptr[i] = r; cursor[i] = r; }
    if (i == 0) rowptr[n] = E;
}

__global__ void k_fill(const int* __restrict__ src, const int* __restrict__ dst,
                       int* __restrict__ cursor, int* __restrict__ csr_src, int E) {
    int e = blockIdx.x * blockDim.x + threadIdx.x;
    if (e >= E) return;
    int p = atomicAdd(&cursor[dst[e]], 1);
    csr_src[p] = src[e];
}

__global__ void k_fill_w(const int* __restrict__ src, const int* __restrict__ dst,
                         const float* __restrict__ w, int* __restrict__ cursor,
                         int* __restrict__ csr_src, float* __restrict__ csr_w, int E) {
    int e = blockIdx.x * blockDim.x + threadIdx.x;
    if (e >= E) return;
    int p = atomicAdd(&cursor[dst[e]], 1);
    csr_src[p] = src[e];
    csr_w[p] = w[e];
}

// ================= gathers =================

// 5-channel gcn-normalized gather: one thread per dst node, 4-edge unroll
__global__ void k_gather5(const float* __restrict__ x, const int* __restrict__ rowptr,
                          const int* __restrict__ csr_src, const float* __restrict__ dinv,
                          float* __restrict__ out, int n) {
    int d = blockIdx.x * blockDim.x + threadIdx.x;
    if (d >= n) return;
    int b = rowptr[d], e = rowptr[d + 1];
    float dd = dinv[d];
    float a0 = 0, a1 = 0, a2 = 0, a3 = 0, a4 = 0;
    int p = b;
    for (; p + 4 <= e; p += 4) {
        int s0 = csr_src[p], s1 = csr_src[p+1], s2 = csr_src[p+2], s3 = csr_src[p+3];
        const float* x0 = x + (size_t)s0 * 5;
        const float* x1 = x + (size_t)s1 * 5;
        const float* x2 = x + (size_t)s2 * 5;
        const float* x3 = x + (size_t)s3 * 5;
        float w0 = dd * dinv[s0], w1 = dd * dinv[s1], w2 = dd * dinv[s2], w3 = dd * dinv[s3];
        a0 += x0[0]*w0 + x1[0]*w1 + x2[0]*w2 + x3[0]*w3;
        a1 += x0[1]*w0 + x1[1]*w1 + x2[1]*w2 + x3[1]*w3;
        a2 += x0[2]*w0 + x1[2]*w1 + x2[2]*w2 + x3[2]*w3;
        a3 += x0[3]*w0 + x1[3]*w1 + x2[3]*w2 + x3[3]*w3;
        a4 += x0[4]*w0 + x1[4]*w1 + x2[4]*w2 + x3[4]*w3;
    }
    for (; p < e; p++) {
        int s = csr_src[p];
        float w = dd * dinv[s];
        const float* xp = x + (size_t)s * 5;
        a0 += xp[0]*w; a1 += xp[1]*w; a2 += xp[2]*w; a3 += xp[3]*w; a4 += xp[4]*w;
    }
    float* op = out + (size_t)d * 5;
    op[0] = a0; op[1] = a1; op[2] = a2; op[3] = a3; op[4] = a4;
}

// 64-channel gather: one wave per dst row; 4 groups x 16 lanes x float4.
// MODE: 0 = plain sum, 1 = per-edge weight, 2 = symmetric gcn norm
template<int MODE>
__global__ void k_gather64(const float* __restrict__ x, const int* __restrict__ rowptr,
                           const int* __restrict__ csr_src, const float* __restrict__ csr_w,
                           const float* __restrict__ dinv, float* __restrict__ out, int n) {
    int wid = (int)(((long long)blockIdx.x * blockDim.x + threadIdx.x) >> 6);
    if (wid >= n) return;
    int lane = threadIdx.x & 63;
    int g = lane >> 4, q = lane & 15;
    int b = rowptr[wid], e = rowptr[wid + 1];
    float dd = (MODE == 2) ? dinv[wid] : 0.f;
    float4 acc = make_float4(0.f, 0.f, 0.f, 0.f);
    for (int p = b + g; p < e; p += 4) {
        int s = csr_src[p];
        float4 v = ((const float4*)(x + (size_t)s * 64))[q];
        if (MODE == 0) {
            acc.x += v.x; acc.y += v.y; acc.z += v.z; acc.w += v.w;
        } else {
            float w = (MODE == 1) ? csr_w[p] : dd * dinv[s];
            acc.x += v.x * w; acc.y += v.y * w; acc.z += v.z * w; acc.w += v.w * w;
        }
    }
    // butterfly-sum the 4 group partials (lanes l, l^16, l^32, l^48)
    #pragma unroll
    for (int off = 16; off < 64; off <<= 1) {
        acc.x += __shfl_xor(acc.x, off, 64);
        acc.y += __shfl_xor(acc.y, off, 64);
        acc.z += __shfl_xor(acc.z, off, 64);
        acc.w += __shfl_xor(acc.w, off, 64);
    }
    if (g == 0) ((float4*)(out + (size_t)wid * 64))[q] = acc;
}

// ================= dense combines =================

// gx = relu(b + x@W0 + h1@W1 + h2@W2), x,h1,h2:[n,5], W:[3,5,64]
__global__ void k_tag1(const float* __restrict__ x, const float* __restrict__ h1,
                       const float* __restrict__ h2, const float* __restrict__ W,
                       const float* __restrict__ b, float* __restrict__ gx, int n) {
    int t = blockIdx.x * blockDim.x + threadIdx.x;
    if (t >= n * 64) return;
    int i = t >> 6, j = t & 63;
    float acc = b[j];
    #pragma unroll
    for (int k = 0; k < 5; k++) {
        acc += x [i * 5 + k] * W[      k * 64 + j];
        acc += h1[i * 5 + k] * W[320 + k * 64 + j];
        acc += h2[i * 5 + k] * W[640 + k * 64 + j];
    }
    gx[t] = fmaxf(acc, 0.f);
}

// sx = relu(gc_b + agg@W_rel + state_x@W_root)
__global__ void k_gc(const float* __restrict__ agg, const float* __restrict__ sxin,
                     const float* __restrict__ Wrel, const float* __restrict__ Wroot,
                     const float* __restrict__ b, float* __restrict__ out, int n) {
    int t = blockIdx.x * blockDim.x + threadIdx.x;
    if (t >= n * 64) return;
    int i = t >> 6, j = t & 63;
    float acc = b[j];
    #pragma unroll 8
    for (int k = 0; k < 64; k++) acc += agg[i * 64 + k] * Wrel[k * 64 + j];
    #pragma unroll
    for (int k = 0; k < 6;  k++) acc += sxin[i * 6 + k] * Wroot[k * 64 + j];
    out[t] = fmaxf(acc, 0.f);
}

// sx2 = relu(b_l + (ssum/max(cnt,1))@W_l + sx@W_r); cnt from rowptr diff
__global__ void k_sage(const float* __restrict__ ssum, const int* __restrict__ rowptr_in,
                       const float* __restrict__ sx, const float* __restrict__ Wl,
                       const float* __restrict__ Wr, const float* __restrict__ bl,
                       float* __restrict__ out, int n) {
    int t = blockIdx.x * blockDim.x + threadIdx.x;
    if (t >= n * 64) return;
    int i = t >> 6, j = t & 63;
    float cnt = (float)(rowptr_in[i + 1] - rowptr_in[i]);
    float r = 1.f / fmaxf(cnt, 1.f);
    float acc = bl[j];
    #pragma unroll 8
    for (int k = 0; k < 64; k++) {
        acc += (ssum[i * 64 + k] * r) * Wl[k * 64 + j];
        acc += sx[i * 64 + k] * Wr[k * 64 + j];
    }
    out[t] = fmaxf(acc, 0.f);
}

// out = b + x@W   (W 64x64)
__global__ void k_mm_init(const float* __restrict__ x, const float* __restrict__ W,
                          const float* __restrict__ b, float* __restrict__ out, int n) {
    int t = blockIdx.x * blockDim.x + threadIdx.x;
    if (t >= n * 64) return;
    int i = t >> 6, j = t & 63;
    float acc = b[j];
    #pragma unroll 8
    for (int k = 0; k < 64; k++) acc += x[i * 64 + k] * W[k * 64 + j];
    out[t] = acc;
}

// out += h@W
__global__ void k_mm_acc(const float* __restrict__ h, const float* __restrict__ W,
                         float* __restrict__ out, int n) {
    int t = blockIdx.x * blockDim.x + threadIdx.x;
    if (t >= n * 64) return;
    int i = t >> 6, j = t & 63;
    float acc = 0.f;
    #pragma unroll 8
    for (int k = 0; k < 64; k++) acc += h[i * 64 + k] * W[k * 64 + j];
    out[t] += acc;
}

// out = relu(sx3) @ lin_W + lin_b
__global__ void k_final(const float* __restrict__ x, const float* __restrict__ W,
                        const float* __restrict__ b, float* __restrict__ out, int n) {
    int t = blockIdx.x * blockDim.x + threadIdx.x;
    if (t >= n * 8) return;
    int i = t >> 3, o = t & 7;
    float acc = b[o];
    #pragma unroll 8
    for (int k = 0; k < 64; k++) acc += fmaxf(x[i * 64 + k], 0.f) * W[k * 8 + o];
    out[t] = acc;
}

static inline unsigned gblk(long long n) { return (unsigned)((n + BLK - 1) / BLK); }

// build CSR rowptr+cursor for (dst,E,N); optional dinv from degree
static void build_csr_base(const int* dst, int E, int N,
                           int* rowptr, int* cursor, int* bsum, float* dinv,
                           hipStream_t stream) {
    hipMemsetAsync(cursor, 0, (size_t)N * sizeof(int), stream);
    k_hist<<<gblk(E), BLK, 0, stream>>>(dst, cursor, E);
    int nb = (N + 255) / 256;
    k_scan_block<<<nb, 256, 0, stream>>>(cursor, rowptr, bsum, dinv, N);
    k_scan_top<<<1, 1024, 0, stream>>>(bsum, nb);
    k_scan_add<<<gblk(N), BLK, 0, stream>>>(rowptr, bsum, cursor, N, E);
}

extern "C" void kernel_launch(void* const* d_in, const int* in_sizes, int n_in,
                              void* d_out, int out_size, void* d_ws, size_t ws_size,
                              hipStream_t stream) {
    const float* game_x  = (const float*)d_in[0];
    const float* state_x = (const float*)d_in[1];
    const int*   ei_vv   = (const int*)d_in[2];
    const int*   ei_h    = (const int*)d_in[3];
    const float* ea_h    = (const float*)d_in[4];
    const int*   ei_in   = (const int*)d_in[5];
    const int*   ei_ss   = (const int*)d_in[6];
    const float* tag1_W  = (const float*)d_in[7];
    const float* tag1_b  = (const float*)d_in[8];
    const float* tag2_W  = (const float*)d_in[9];
    const float* tag2_b  = (const float*)d_in[10];
    const float* gc_Wrel = (const float*)d_in[11];
    const float* gc_b    = (const float*)d_in[12];
    const float* gc_Wroot= (const float*)d_in[13];
    const float* sage_Wl = (const float*)d_in[14];
    const float* sage_bl = (const float*)d_in[15];
    const float* sage_Wr = (const float*)d_in[16];
    const float* lin_W   = (const float*)d_in[17];
    const float* lin_b   = (const float*)d_in[18];

    const int NV  = in_sizes[0] / 5;
    const int NS  = in_sizes[1] / 6;
    const int EVV = in_sizes[2] / 2;
    const int EH  = in_sizes[3] / 2;
    const int EIN = in_sizes[5] / 2;
    const int ESS = in_sizes[6] / 2;

    const int *vv_s = ei_vv,  *vv_d = ei_vv + EVV;
    const int *h_s  = ei_h,   *h_d  = ei_h  + EH;
    const int *in_s = ei_in,  *in_d = ei_in + EIN;
    const int *ss_s = ei_ss,  *ss_d = ei_ss + ESS;

    // ---------------- workspace layout (4-byte words) ----------------
    float* wsf = (float*)d_ws;
    size_t o = 0;
    float* gx   = wsf + o; o += (size_t)NV * 64;                        // sx3 reuses this
    float* B1   = wsf + o; o += (size_t)NS * 64 + ((size_t)NS * 2 + (size_t)EIN + 64); // agg | (inCSR+ssum) | hA
    float* B2   = wsf + o; o += (size_t)NS * 64;                        // sx | hB
    float* B4   = wsf + o; o += (size_t)NS * 64;                        // h1v+h2v | hCSR | sx2
    float* pool = wsf + o; o += (size_t)NV + (size_t)NV + (size_t)EVV + 64; // vv CSR | ss CSR
    float* dinv = wsf + o; o += (size_t)NV;                             // dinv_v | dinv_s
    int*   bsum = (int*)(wsf + o); o += 1024;

    // ================= Stage A: TAGConv1 on v-v =================
    int* vvrp  = (int*)pool;
    int* vvcur = vvrp + NV + 1;
    int* vvsrc = vvcur + NV;
    build_csr_base(vv_d, EVV, NV, vvrp, vvcur, bsum, dinv, stream);
    k_fill<<<gblk(EVV), BLK, 0, stream>>>(vv_s, vv_d, vvcur, vvsrc, EVV);

    float* h1v = B4;
    float* h2v = B4 + (size_t)NV * 5;
    k_gather5<<<gblk(NV), BLK, 0, stream>>>(game_x, vvrp, vvsrc, dinv, h1v, NV);
    k_gather5<<<gblk(NV), BLK, 0, stream>>>(h1v,    vvrp, vvsrc, dinv, h2v, NV);
    k_tag1<<<gblk((long long)NV * 64), BLK, 0, stream>>>(game_x, h1v, h2v, tag1_W, tag1_b, gx, NV);

    // ================= Stage B: GraphConv (weighted) =================
    int*   hrp  = (int*)B4;                 // h1v/h2v dead
    int*   hcur = hrp + NS + 1;
    int*   hsrc = hcur + NS;
    float* hw   = (float*)(hsrc + EH);
    build_csr_base(h_d, EH, NS, hrp, hcur, bsum, nullptr, stream);
    k_fill_w<<<gblk(EH), BLK, 0, stream>>>(h_s, h_d, ea_h, hcur, hsrc, hw, EH);

    float* agg = B1;
    float* sx  = B2;
    k_gather64<1><<<gblk((long long)NS * 64), BLK, 0, stream>>>(gx, hrp, hsrc, hw, nullptr, agg, NS);
    k_gc<<<gblk((long long)NS * 64), BLK, 0, stream>>>(agg, state_x, gc_Wrel, gc_Wroot, gc_b, sx, NS);

    // ================= Stage C: SAGE mean =================
    int*   inrp  = (int*)B1;                // agg dead
    int*   incur = inrp + NS + 1;
    int*   insrc = incur + NS;
    float* ssum  = B1 + ((size_t)NS * 2 + (size_t)EIN + 32);
    build_csr_base(in_d, EIN, NS, inrp, incur, bsum, nullptr, stream);
    k_fill<<<gblk(EIN), BLK, 0, stream>>>(in_s, in_d, incur, insrc, EIN);
    k_gather64<0><<<gblk((long long)NS * 64), BLK, 0, stream>>>(gx, inrp, insrc, nullptr, nullptr, ssum, NS);

    float* sx2 = B4;                        // h CSR dead
    k_sage<<<gblk((long long)NS * 64), BLK, 0, stream>>>(ssum, inrp, sx, sage_Wl, sage_Wr, sage_bl, sx2, NS);

    // ================= Stage D: TAGConv2 on s-s (K=3) =================
    int* ssrp  = (int*)pool;                // vv CSR dead
    int* sscur = ssrp + NS + 1;
    int* sssrc = sscur + NS;
    build_csr_base(ss_d, ESS, NS, ssrp, sscur, bsum, dinv, stream);  // dinv_v dead -> dinv_s
    k_fill<<<gblk(ESS), BLK, 0, stream>>>(ss_s, ss_d, sscur, sssrc, ESS);

    float* sx3 = gx;                        // gx dead after stage C gather
    float* hA  = B1;                        // in CSR + ssum dead
    float* hB  = B2;                        // sx dead

    k_mm_init<<<gblk((long long)NS * 64), BLK, 0, stream>>>(sx2, tag2_W, tag2_b, sx3, NS);
    k_gather64<2><<<gblk((long long)NS * 64), BLK, 0, stream>>>(sx2, ssrp, sssrc, nullptr, dinv, hA, NS);
    k_mm_acc<<<gblk((long long)NS * 64), BLK, 0, stream>>>(hA, tag2_W + 4096, sx3, NS);
    k_gather64<2><<<gblk((long long)NS * 64), BLK, 0, stream>>>(hA, ssrp, sssrc, nullptr, dinv, hB, NS);
    k_mm_acc<<<gblk((long long)NS * 64), BLK, 0, stream>>>(hB, tag2_W + 8192, sx3, NS);
    k_gather64<2><<<gblk((long long)NS * 64), BLK, 0, stream>>>(hB, ssrp, sssrc, nullptr, dinv, hA, NS);
    k_mm_acc<<<gblk((long long)NS * 64), BLK, 0, stream>>>(hA, tag2_W + 12288, sx3, NS);

    // ================= Stage E: final linear (relu fused) =================
    k_final<<<gblk((long long)NS * 8), BLK, 0, stream>>>(sx3, lin_W, lin_b, (float*)d_out, NS);
}

// Round 4
// 1035.918 us; speedup vs baseline: 2.0153x; 1.0667x over previous
//
#include <hip/hip_runtime.h>

#define BLK 256

// broadcast lane l of v across the wave (wave-uniform l)
__device__ __forceinline__ float bcast(float v, int l) {
    return __int_as_float(__builtin_amdgcn_readlane(__float_as_int(v), l));
}

// ================= CSR construction =================

__global__ void k_hist(const int* __restrict__ dst, int* __restrict__ deg, int E) {
    int e = blockIdx.x * blockDim.x + threadIdx.x;
    if (e < E) atomicAdd(&deg[dst[e]], 1);
}

// per-256-block exclusive scan; block sums out; optional dinv = rsqrt(deg)
__global__ void k_scan_block(const int* __restrict__ deg, int* __restrict__ excl,
                             int* __restrict__ bsum, float* __restrict__ dinv, int n) {
    __shared__ int sh[256];
    int i = blockIdx.x * 256 + threadIdx.x;
    int v = (i < n) ? deg[i] : 0;
    if (dinv && i < n) dinv[i] = v > 0 ? rsqrtf((float)v) : 0.f;
    sh[threadIdx.x] = v; __syncthreads();
    for (int off = 1; off < 256; off <<= 1) {
        int t = (threadIdx.x >= (unsigned)off) ? sh[threadIdx.x - off] : 0;
        __syncthreads();
        sh[threadIdx.x] += t; __syncthreads();
    }
    if (i < n) excl[i] = sh[threadIdx.x] - v;
    if (threadIdx.x == 255) bsum[blockIdx.x] = sh[255];
}

__global__ void k_scan_top(int* __restrict__ bsum, int nb) {
    __shared__ int sh[1024];
    int tid = threadIdx.x;
    int v = (tid < nb) ? bsum[tid] : 0;
    sh[tid] = v; __syncthreads();
    for (int off = 1; off < 1024; off <<= 1) {
        int t = (tid >= off) ? sh[tid - off] : 0;
        __syncthreads();
        sh[tid] += t; __syncthreads();
    }
    if (tid < nb) bsum[tid] = sh[tid] - v;
}

__global__ void k_scan_add(int* __restrict__ rowptr, const int* __restrict__ bsum,
                           int* __restrict__ cursor, int n, int E) {
    int i = blockIdx.x * blockDim.x + threadIdx.x;
    if (i < n) { int r = rowptr[i] + bsum[i >> 8]; rowptr[i] = r; cursor[i] = r; }
    if (i == 0) rowptr[n] = E;
}

__global__ void k_fill(const int* __restrict__ src, const int* __restrict__ dst,
                       int* __restrict__ cursor, int* __restrict__ csr_src, int E) {
    int e = blockIdx.x * blockDim.x + threadIdx.x;
    if (e >= E) return;
    int p = atomicAdd(&cursor[dst[e]], 1);
    csr_src[p] = src[e];
}

__global__ void k_fill_w(const int* __restrict__ src, const int* __restrict__ dst,
                         const float* __restrict__ w, int* __restrict__ cursor,
                         int* __restrict__ csr_src, float* __restrict__ csr_w, int E) {
    int e = blockIdx.x * blockDim.x + threadIdx.x;
    if (e >= E) return;
    int p = atomicAdd(&cursor[dst[e]], 1);
    csr_src[p] = src[e];
    csr_w[p] = w[e];
}

// ================= gathers =================

__global__ void k_gather5(const float* __restrict__ x, const int* __restrict__ rowptr,
                          const int* __restrict__ csr_src, const float* __restrict__ dinv,
                          float* __restrict__ out, int n) {
    int d = blockIdx.x * blockDim.x + threadIdx.x;
    if (d >= n) return;
    int b = rowptr[d], e = rowptr[d + 1];
    float dd = dinv[d];
    float a0 = 0, a1 = 0, a2 = 0, a3 = 0, a4 = 0;
    int p = b;
    for (; p + 4 <= e; p += 4) {
        int s0 = csr_src[p], s1 = csr_src[p+1], s2 = csr_src[p+2], s3 = csr_src[p+3];
        const float* x0 = x + (size_t)s0 * 5;
        const float* x1 = x + (size_t)s1 * 5;
        const float* x2 = x + (size_t)s2 * 5;
        const float* x3 = x + (size_t)s3 * 5;
        float w0 = dd * dinv[s0], w1 = dd * dinv[s1], w2 = dd * dinv[s2], w3 = dd * dinv[s3];
        a0 += x0[0]*w0 + x1[0]*w1 + x2[0]*w2 + x3[0]*w3;
        a1 += x0[1]*w0 + x1[1]*w1 + x2[1]*w2 + x3[1]*w3;
        a2 += x0[2]*w0 + x1[2]*w1 + x2[2]*w2 + x3[2]*w3;
        a3 += x0[3]*w0 + x1[3]*w1 + x2[3]*w2 + x3[3]*w3;
        a4 += x0[4]*w0 + x1[4]*w1 + x2[4]*w2 + x3[4]*w3;
    }
    for (; p < e; p++) {
        int s = csr_src[p];
        float w = dd * dinv[s];
        const float* xp = x + (size_t)s * 5;
        a0 += xp[0]*w; a1 += xp[1]*w; a2 += xp[2]*w; a3 += xp[3]*w; a4 += xp[4]*w;
    }
    float* op = out + (size_t)d * 5;
    op[0] = a0; op[1] = a1; op[2] = a2; op[3] = a3; op[4] = a4;
}

// 64-channel gather: one wave per dst row; 4 groups x 16 lanes x float4.
// MODE: 0 = plain sum, 1 = per-edge weight, 2 = symmetric gcn norm
template<int MODE>
__global__ void k_gather64(const float* __restrict__ x, const int* __restrict__ rowptr,
                           const int* __restrict__ csr_src, const float* __restrict__ csr_w,
                           const float* __restrict__ dinv, float* __restrict__ out, int n) {
    int wid = (int)(((long long)blockIdx.x * blockDim.x + threadIdx.x) >> 6);
    if (wid >= n) return;
    int lane = threadIdx.x & 63;
    int g = lane >> 4, q = lane & 15;
    int b = rowptr[wid], e = rowptr[wid + 1];
    float dd = (MODE == 2) ? dinv[wid] : 0.f;
    float4 acc = make_float4(0.f, 0.f, 0.f, 0.f);
    for (int p = b + g; p < e; p += 4) {
        int s = csr_src[p];
        float4 v = ((const float4*)(x + (size_t)s * 64))[q];
        if (MODE == 0) {
            acc.x += v.x; acc.y += v.y; acc.z += v.z; acc.w += v.w;
        } else {
            float w = (MODE == 1) ? csr_w[p] : dd * dinv[s];
            acc.x += v.x * w; acc.y += v.y * w; acc.z += v.z * w; acc.w += v.w * w;
        }
    }
    #pragma unroll
    for (int off = 16; off < 64; off <<= 1) {
        acc.x += __shfl_xor(acc.x, off, 64);
        acc.y += __shfl_xor(acc.y, off, 64);
        acc.z += __shfl_xor(acc.z, off, 64);
        acc.w += __shfl_xor(acc.w, off, 64);
    }
    if (g == 0) ((float4*)(out + (size_t)wid * 64))[q] = acc;
}

// ================= dense combines (wave-tiled register GEMMs) =================
// One wave computes 4 rows x 64 cols. Lane = output column. Input rows live in
// registers; inner loop broadcasts row elements via v_readlane (no x loads).

// gx = relu(b + x@W0 + h1@W1 + h2@W2), x,h1,h2:[n,5], W:[3,5,64]
// Pack the three 5-wide rows into one register: lanes 0-4 = x, 8-12 = h1, 16-20 = h2.
__global__ void k_tag1_w(const float* __restrict__ x, const float* __restrict__ h1,
                         const float* __restrict__ h2, const float* __restrict__ W,
                         const float* __restrict__ b, float* __restrict__ out, int n) {
    int wv = (int)(((long long)blockIdx.x * blockDim.x + threadIdx.x) >> 6);
    int lane = threadIdx.x & 63;
    int i0 = wv * 4;
    if (i0 >= n) return;
    float v[4], acc[4];
    #pragma unroll
    for (int r = 0; r < 4; r++) {
        int i = (i0 + r < n) ? i0 + r : n - 1;
        float t = 0.f;
        if (lane < 5)                     t = x [(size_t)i * 5 + lane];
        else if (lane >= 8 && lane < 13)  t = h1[(size_t)i * 5 + lane - 8];
        else if (lane >= 16 && lane < 21) t = h2[(size_t)i * 5 + lane - 16];
        v[r] = t;
        acc[r] = b[lane];
    }
    #pragma unroll
    for (int m = 0; m < 3; m++) {
        #pragma unroll
        for (int k = 0; k < 5; k++) {
            float wk = W[(m * 5 + k) * 64 + lane];
            #pragma unroll
            for (int r = 0; r < 4; r++) acc[r] += bcast(v[r], m * 8 + k) * wk;
        }
    }
    #pragma unroll
    for (int r = 0; r < 4; r++)
        if (i0 + r < n) out[(size_t)(i0 + r) * 64 + lane] = fmaxf(acc[r], 0.f);
}

// sx = relu(b + agg@Wrel(64x64) + state@Wroot(6x64))
__global__ void k_gc_w(const float* __restrict__ agg, const float* __restrict__ st,
                       const float* __restrict__ Wrel, const float* __restrict__ Wroot,
                       const float* __restrict__ b, float* __restrict__ out, int n) {
    int wv = (int)(((long long)blockIdx.x * blockDim.x + threadIdx.x) >> 6);
    int lane = threadIdx.x & 63;
    int i0 = wv * 4;
    if (i0 >= n) return;
    float xs[4], sr[4], acc[4];
    #pragma unroll
    for (int r = 0; r < 4; r++) {
        int i = (i0 + r < n) ? i0 + r : n - 1;
        xs[r] = agg[(size_t)i * 64 + lane];
        sr[r] = (lane < 6) ? st[(size_t)i * 6 + lane] : 0.f;
        acc[r] = b[lane];
    }
    #pragma unroll
    for (int k = 0; k < 64; k++) {
        float wk = Wrel[k * 64 + lane];
        #pragma unroll
        for (int r = 0; r < 4; r++) acc[r] += bcast(xs[r], k) * wk;
    }
    #pragma unroll
    for (int k = 0; k < 6; k++) {
        float wk = Wroot[k * 64 + lane];
        #pragma unroll
        for (int r = 0; r < 4; r++) acc[r] += bcast(sr[r], k) * wk;
    }
    #pragma unroll
    for (int r = 0; r < 4; r++)
        if (i0 + r < n) out[(size_t)(i0 + r) * 64 + lane] = fmaxf(acc[r], 0.f);
}

// sx2 = relu(bl + (ssum/max(cnt,1))@Wl + sx@Wr); cnt from rowptr diff
__global__ void k_sage_w(const float* __restrict__ ssum, const int* __restrict__ rp,
                         const float* __restrict__ sx, const float* __restrict__ Wl,
                         const float* __restrict__ Wr, const float* __restrict__ bl,
                         float* __restrict__ out, int n) {
    int wv = (int)(((long long)blockIdx.x * blockDim.x + threadIdx.x) >> 6);
    int lane = threadIdx.x & 63;
    int i0 = wv * 4;
    if (i0 >= n) return;
    float xs[4], ys[4], acc[4];
    #pragma unroll
    for (int r = 0; r < 4; r++) {
        int i = (i0 + r < n) ? i0 + r : n - 1;
        float cnt = (float)(rp[i + 1] - rp[i]);
        float rs = 1.f / fmaxf(cnt, 1.f);
        xs[r] = ssum[(size_t)i * 64 + lane] * rs;
        ys[r] = sx[(size_t)i * 64 + lane];
        acc[r] = bl[lane];
    }
    #pragma unroll
    for (int k = 0; k < 64; k++) {
        float wl = Wl[k * 64 + lane];
        float wr = Wr[k * 64 + lane];
        #pragma unroll
        for (int r = 0; r < 4; r++)
            acc[r] += bcast(xs[r], k) * wl + bcast(ys[r], k) * wr;
    }
    #pragma unroll
    for (int r = 0; r < 4; r++)
        if (i0 + r < n) out[(size_t)(i0 + r) * 64 + lane] = fmaxf(acc[r], 0.f);
}

// INIT: out = bias + x@W ; else: out += x@W   (W 64x64)
template<bool INIT>
__global__ void k_mm_w(const float* __restrict__ x, const float* __restrict__ W,
                       const float* __restrict__ bias, float* __restrict__ out, int n) {
    int wv = (int)(((long long)blockIdx.x * blockDim.x + threadIdx.x) >> 6);
    int lane = threadIdx.x & 63;
    int i0 = wv * 4;
    if (i0 >= n) return;
    float xs[4], acc[4];
    #pragma unroll
    for (int r = 0; r < 4; r++) {
        int i = (i0 + r < n) ? i0 + r : n - 1;
        xs[r] = x[(size_t)i * 64 + lane];
        acc[r] = INIT ? bias[lane] : out[(size_t)i * 64 + lane];
    }
    #pragma unroll
    for (int k = 0; k < 64; k++) {
        float wk = W[k * 64 + lane];
        #pragma unroll
        for (int r = 0; r < 4; r++) acc[r] += bcast(xs[r], k) * wk;
    }
    #pragma unroll
    for (int r = 0; r < 4; r++)
        if (i0 + r < n) out[(size_t)(i0 + r) * 64 + lane] = acc[r];
}

// out = relu(sx3) @ lin_W + lin_b  (64 -> 8)
__global__ void k_final(const float* __restrict__ x, const float* __restrict__ W,
                        const float* __restrict__ b, float* __restrict__ out, int n) {
    int t = blockIdx.x * blockDim.x + threadIdx.x;
    if (t >= n * 8) return;
    int i = t >> 3, o = t & 7;
    float acc = b[o];
    #pragma unroll 8
    for (int k = 0; k < 64; k++) acc += fmaxf(x[i * 64 + k], 0.f) * W[k * 8 + o];
    out[t] = acc;
}

static inline unsigned gblk(long long n) { return (unsigned)((n + BLK - 1) / BLK); }
// grid for wave-per-4-rows kernels: one wave (64 thr) per 4 rows
static inline unsigned gwv4(long long n) { return gblk(((n + 3) / 4) * 64); }

static void build_csr_base(const int* dst, int E, int N,
                           int* rowptr, int* cursor, int* bsum, float* dinv,
                           hipStream_t stream) {
    hipMemsetAsync(cursor, 0, (size_t)N * sizeof(int), stream);
    k_hist<<<gblk(E), BLK, 0, stream>>>(dst, cursor, E);
    int nb = (N + 255) / 256;
    k_scan_block<<<nb, 256, 0, stream>>>(cursor, rowptr, bsum, dinv, N);
    k_scan_top<<<1, 1024, 0, stream>>>(bsum, nb);
    k_scan_add<<<gblk(N), BLK, 0, stream>>>(rowptr, bsum, cursor, N, E);
}

extern "C" void kernel_launch(void* const* d_in, const int* in_sizes, int n_in,
                              void* d_out, int out_size, void* d_ws, size_t ws_size,
                              hipStream_t stream) {
    const float* game_x  = (const float*)d_in[0];
    const float* state_x = (const float*)d_in[1];
    const int*   ei_vv   = (const int*)d_in[2];
    const int*   ei_h    = (const int*)d_in[3];
    const float* ea_h    = (const float*)d_in[4];
    const int*   ei_in   = (const int*)d_in[5];
    const int*   ei_ss   = (const int*)d_in[6];
    const float* tag1_W  = (const float*)d_in[7];
    const float* tag1_b  = (const float*)d_in[8];
    const float* tag2_W  = (const float*)d_in[9];
    const float* tag2_b  = (const float*)d_in[10];
    const float* gc_Wrel = (const float*)d_in[11];
    const float* gc_b    = (const float*)d_in[12];
    const float* gc_Wroot= (const float*)d_in[13];
    const float* sage_Wl = (const float*)d_in[14];
    const float* sage_bl = (const float*)d_in[15];
    const float* sage_Wr = (const float*)d_in[16];
    const float* lin_W   = (const float*)d_in[17];
    const float* lin_b   = (const float*)d_in[18];

    const int NV  = in_sizes[0] / 5;
    const int NS  = in_sizes[1] / 6;
    const int EVV = in_sizes[2] / 2;
    const int EH  = in_sizes[3] / 2;
    const int EIN = in_sizes[5] / 2;
    const int ESS = in_sizes[6] / 2;

    const int *vv_s = ei_vv,  *vv_d = ei_vv + EVV;
    const int *h_s  = ei_h,   *h_d  = ei_h  + EH;
    const int *in_s = ei_in,  *in_d = ei_in + EIN;
    const int *ss_s = ei_ss,  *ss_d = ei_ss + ESS;

    // ---------------- workspace layout (4-byte words) ----------------
    float* wsf = (float*)d_ws;
    size_t o = 0;
    float* gx   = wsf + o; o += (size_t)NV * 64;                        // sx3 reuses this
    float* B1   = wsf + o; o += (size_t)NS * 64 + ((size_t)NS * 2 + (size_t)EIN + 64); // agg | (inCSR+ssum) | hA
    float* B2   = wsf + o; o += (size_t)NS * 64;                        // sx | hB
    float* B4   = wsf + o; o += (size_t)NS * 64;                        // h1v+h2v | hCSR | sx2
    float* pool = wsf + o; o += (size_t)NV + (size_t)NV + (size_t)EVV + 64; // vv CSR | ss CSR
    float* dinv = wsf + o; o += (size_t)NV;                             // dinv_v | dinv_s
    int*   bsum = (int*)(wsf + o); o += 1024;

    // ================= Stage A: TAGConv1 on v-v =================
    int* vvrp  = (int*)pool;
    int* vvcur = vvrp + NV + 1;
    int* vvsrc = vvcur + NV;
    build_csr_base(vv_d, EVV, NV, vvrp, vvcur, bsum, dinv, stream);
    k_fill<<<gblk(EVV), BLK, 0, stream>>>(vv_s, vv_d, vvcur, vvsrc, EVV);

    float* h1v = B4;
    float* h2v = B4 + (size_t)NV * 5;
    k_gather5<<<gblk(NV), BLK, 0, stream>>>(game_x, vvrp, vvsrc, dinv, h1v, NV);
    k_gather5<<<gblk(NV), BLK, 0, stream>>>(h1v,    vvrp, vvsrc, dinv, h2v, NV);
    k_tag1_w<<<gwv4(NV), BLK, 0, stream>>>(game_x, h1v, h2v, tag1_W, tag1_b, gx, NV);

    // ================= Stage B: GraphConv (weighted) =================
    int*   hrp  = (int*)B4;                 // h1v/h2v dead
    int*   hcur = hrp + NS + 1;
    int*   hsrc = hcur + NS;
    float* hw   = (float*)(hsrc + EH);
    build_csr_base(h_d, EH, NS, hrp, hcur, bsum, nullptr, stream);
    k_fill_w<<<gblk(EH), BLK, 0, stream>>>(h_s, h_d, ea_h, hcur, hsrc, hw, EH);

    float* agg = B1;
    float* sx  = B2;
    k_gather64<1><<<gblk((long long)NS * 64), BLK, 0, stream>>>(gx, hrp, hsrc, hw, nullptr, agg, NS);
    k_gc_w<<<gwv4(NS), BLK, 0, stream>>>(agg, state_x, gc_Wrel, gc_Wroot, gc_b, sx, NS);

    // ================= Stage C: SAGE mean =================
    int*   inrp  = (int*)B1;                // agg dead
    int*   incur = inrp + NS + 1;
    int*   insrc = incur + NS;
    float* ssum  = B1 + ((size_t)NS * 2 + (size_t)EIN + 32);
    build_csr_base(in_d, EIN, NS, inrp, incur, bsum, nullptr, stream);
    k_fill<<<gblk(EIN), BLK, 0, stream>>>(in_s, in_d, incur, insrc, EIN);
    k_gather64<0><<<gblk((long long)NS * 64), BLK, 0, stream>>>(gx, inrp, insrc, nullptr, nullptr, ssum, NS);

    float* sx2 = B4;                        // h CSR dead
    k_sage_w<<<gwv4(NS), BLK, 0, stream>>>(ssum, inrp, sx, sage_Wl, sage_Wr, sage_bl, sx2, NS);

    // ================= Stage D: TAGConv2 on s-s (K=3) =================
    int* ssrp  = (int*)pool;                // vv CSR dead
    int* sscur = ssrp + NS + 1;
    int* sssrc = sscur + NS;
    build_csr_base(ss_d, ESS, NS, ssrp, sscur, bsum, dinv, stream);  // dinv_v dead -> dinv_s
    k_fill<<<gblk(ESS), BLK, 0, stream>>>(ss_s, ss_d, sscur, sssrc, ESS);

    float* sx3 = gx;                        // gx dead after stage C gather
    float* hA  = B1;                        // in CSR + ssum dead
    float* hB  = B2;                        // sx dead

    k_mm_w<true><<<gwv4(NS), BLK, 0, stream>>>(sx2, tag2_W, tag2_b, sx3, NS);
    k_gather64<2><<<gblk((long long)NS * 64), BLK, 0, stream>>>(sx2, ssrp, sssrc, nullptr, dinv, hA, NS);
    k_mm_w<false><<<gwv4(NS), BLK, 0, stream>>>(hA, tag2_W + 4096, nullptr, sx3, NS);
    k_gather64<2><<<gblk((long long)NS * 64), BLK, 0, stream>>>(hA, ssrp, sssrc, nullptr, dinv, hB, NS);
    k_mm_w<false><<<gwv4(NS), BLK, 0, stream>>>(hB, tag2_W + 8192, nullptr, sx3, NS);
    k_gather64<2><<<gblk((long long)NS * 64), BLK, 0, stream>>>(hB, ssrp, sssrc, nullptr, dinv, hA, NS);
    k_mm_w<false><<<gwv4(NS), BLK, 0, stream>>>(hA, tag2_W + 12288, nullptr, sx3, NS);

    // ================= Stage E: final linear (relu fused) =================
    k_final<<<gblk((long long)NS * 8), BLK, 0, stream>>>(sx3, lin_W, lin_b, (float*)d_out, NS);
}

// Round 5
// 920.060 us; speedup vs baseline: 2.2691x; 1.1259x over previous
//
#include <hip/hip_runtime.h>

#define BLK 256

// broadcast lane l of v across the wave (l wave-uniform; dynamic is legal)
__device__ __forceinline__ float bcast(float v, int l) {
    return __int_as_float(__builtin_amdgcn_readlane(__float_as_int(v), l));
}

// ================= CSR construction =================

__global__ void k_hist(const int* __restrict__ dst, int* __restrict__ deg, int E) {
    int e = blockIdx.x * blockDim.x + threadIdx.x;
    if (e < E) atomicAdd(&deg[dst[e]], 1);
}

// per-256-block exclusive scan; block sums out; optional dinv = rsqrt(deg)
__global__ void k_scan_block(const int* __restrict__ deg, int* __restrict__ excl,
                             int* __restrict__ bsum, float* __restrict__ dinv, int n) {
    __shared__ int sh[256];
    int i = blockIdx.x * 256 + threadIdx.x;
    int v = (i < n) ? deg[i] : 0;
    if (dinv && i < n) dinv[i] = v > 0 ? rsqrtf((float)v) : 0.f;
    sh[threadIdx.x] = v; __syncthreads();
    for (int off = 1; off < 256; off <<= 1) {
        int t = (threadIdx.x >= (unsigned)off) ? sh[threadIdx.x - off] : 0;
        __syncthreads();
        sh[threadIdx.x] += t; __syncthreads();
    }
    if (i < n) excl[i] = sh[threadIdx.x] - v;
    if (threadIdx.x == 255) bsum[blockIdx.x] = sh[255];
}

__global__ void k_scan_top(int* __restrict__ bsum, int nb) {
    __shared__ int sh[1024];
    int tid = threadIdx.x;
    int v = (tid < nb) ? bsum[tid] : 0;
    sh[tid] = v; __syncthreads();
    for (int off = 1; off < 1024; off <<= 1) {
        int t = (tid >= off) ? sh[tid - off] : 0;
        __syncthreads();
        sh[tid] += t; __syncthreads();
    }
    if (tid < nb) bsum[tid] = sh[tid] - v;
}

__global__ void k_scan_add(int* __restrict__ rowptr, const int* __restrict__ bsum,
                           int* __restrict__ cursor, int n, int E) {
    int i = blockIdx.x * blockDim.x + threadIdx.x;
    if (i < n) { int r = rowptr[i] + bsum[i >> 8]; rowptr[i] = r; cursor[i] = r; }
    if (i == 0) rowptr[n] = E;
}

__global__ void k_fill(const int* __restrict__ src, const int* __restrict__ dst,
                       int* __restrict__ cursor, int* __restrict__ csr_src, int E) {
    int e = blockIdx.x * blockDim.x + threadIdx.x;
    if (e >= E) return;
    int p = atomicAdd(&cursor[dst[e]], 1);
    csr_src[p] = src[e];
}

__global__ void k_fill_w(const int* __restrict__ src, const int* __restrict__ dst,
                         const float* __restrict__ w, int* __restrict__ cursor,
                         int* __restrict__ csr_src, float* __restrict__ csr_w, int E) {
    int e = blockIdx.x * blockDim.x + threadIdx.x;
    if (e >= E) return;
    int p = atomicAdd(&cursor[dst[e]], 1);
    csr_src[p] = src[e];
    csr_w[p] = w[e];
}

// ================= gathers =================

__global__ void k_gather5(const float* __restrict__ x, const int* __restrict__ rowptr,
                          const int* __restrict__ csr_src, const float* __restrict__ dinv,
                          float* __restrict__ out, int n) {
    int d = blockIdx.x * blockDim.x + threadIdx.x;
    if (d >= n) return;
    int b = rowptr[d], e = rowptr[d + 1];
    float dd = dinv[d];
    float a0 = 0, a1 = 0, a2 = 0, a3 = 0, a4 = 0;
    int p = b;
    for (; p + 4 <= e; p += 4) {
        int s0 = csr_src[p], s1 = csr_src[p+1], s2 = csr_src[p+2], s3 = csr_src[p+3];
        const float* x0 = x + (size_t)s0 * 5;
        const float* x1 = x + (size_t)s1 * 5;
        const float* x2 = x + (size_t)s2 * 5;
        const float* x3 = x + (size_t)s3 * 5;
        float w0 = dd * dinv[s0], w1 = dd * dinv[s1], w2 = dd * dinv[s2], w3 = dd * dinv[s3];
        a0 += x0[0]*w0 + x1[0]*w1 + x2[0]*w2 + x3[0]*w3;
        a1 += x0[1]*w0 + x1[1]*w1 + x2[1]*w2 + x3[1]*w3;
        a2 += x0[2]*w0 + x1[2]*w1 + x2[2]*w2 + x3[2]*w3;
        a3 += x0[3]*w0 + x1[3]*w1 + x2[3]*w2 + x3[3]*w3;
        a4 += x0[4]*w0 + x1[4]*w1 + x2[4]*w2 + x3[4]*w3;
    }
    for (; p < e; p++) {
        int s = csr_src[p];
        float w = dd * dinv[s];
        const float* xp = x + (size_t)s * 5;
        a0 += xp[0]*w; a1 += xp[1]*w; a2 += xp[2]*w; a3 += xp[3]*w; a4 += xp[4]*w;
    }
    float* op = out + (size_t)d * 5;
    op[0] = a0; op[1] = a1; op[2] = a2; op[3] = a3; op[4] = a4;
}

// 64-channel gather: one wave per dst row; 4 groups x 16 lanes x float4.
// MODE: 0 = plain sum, 1 = per-edge weight, 2 = symmetric gcn norm
template<int MODE>
__global__ void k_gather64(const float* __restrict__ x, const int* __restrict__ rowptr,
                           const int* __restrict__ csr_src, const float* __restrict__ csr_w,
                           const float* __restrict__ dinv, float* __restrict__ out, int n) {
    int wid = (int)(((long long)blockIdx.x * blockDim.x + threadIdx.x) >> 6);
    if (wid >= n) return;
    int lane = threadIdx.x & 63;
    int g = lane >> 4, q = lane & 15;
    int b = rowptr[wid], e = rowptr[wid + 1];
    float dd = (MODE == 2) ? dinv[wid] : 0.f;
    float4 acc = make_float4(0.f, 0.f, 0.f, 0.f);
    for (int p = b + g; p < e; p += 4) {
        int s = csr_src[p];
        float4 v = ((const float4*)(x + (size_t)s * 64))[q];
        if (MODE == 0) {
            acc.x += v.x; acc.y += v.y; acc.z += v.z; acc.w += v.w;
        } else {
            float w = (MODE == 1) ? csr_w[p] : dd * dinv[s];
            acc.x += v.x * w; acc.y += v.y * w; acc.z += v.z * w; acc.w += v.w * w;
        }
    }
    #pragma unroll
    for (int off = 16; off < 64; off <<= 1) {
        acc.x += __shfl_xor(acc.x, off, 64);
        acc.y += __shfl_xor(acc.y, off, 64);
        acc.z += __shfl_xor(acc.z, off, 64);
        acc.w += __shfl_xor(acc.w, off, 64);
    }
    if (g == 0) ((float4*)(out + (size_t)wid * 64))[q] = acc;
}

// ================= dense combines (wave-tiled register GEMMs) =================
// One wave computes 4 rows x 64 cols. Lane = output column. Input rows live in
// registers; inner loop broadcasts row elements via v_readlane (no x loads).
// __launch_bounds__(256,4): cap VGPR at 128 (round-4's default 64 + full unroll
// spilled ~200B/thread -> 165MB scratch WRITE). #pragma unroll 8 keeps <=16
// weight loads live at once.

// gx = relu(b + x@W0 + h1@W1 + h2@W2), x,h1,h2:[n,5], W:[3,5,64]
__global__ __launch_bounds__(256, 4)
void k_tag1_w(const float* __restrict__ x, const float* __restrict__ h1,
              const float* __restrict__ h2, const float* __restrict__ W,
              const float* __restrict__ b, float* __restrict__ out, int n) {
    int wv = (int)(((long long)blockIdx.x * blockDim.x + threadIdx.x) >> 6);
    int lane = threadIdx.x & 63;
    int i0 = wv * 4;
    if (i0 >= n) return;
    float v[4], acc[4];
    #pragma unroll
    for (int r = 0; r < 4; r++) {
        int i = (i0 + r < n) ? i0 + r : n - 1;
        float t = 0.f;
        if (lane < 5)                     t = x [(size_t)i * 5 + lane];
        else if (lane >= 8 && lane < 13)  t = h1[(size_t)i * 5 + lane - 8];
        else if (lane >= 16 && lane < 21) t = h2[(size_t)i * 5 + lane - 16];
        v[r] = t;
        acc[r] = b[lane];
    }
    #pragma unroll
    for (int m = 0; m < 3; m++) {
        #pragma unroll
        for (int k = 0; k < 5; k++) {
            float wk = W[(m * 5 + k) * 64 + lane];
            #pragma unroll
            for (int r = 0; r < 4; r++) acc[r] += bcast(v[r], m * 8 + k) * wk;
        }
    }
    #pragma unroll
    for (int r = 0; r < 4; r++)
        if (i0 + r < n) out[(size_t)(i0 + r) * 64 + lane] = fmaxf(acc[r], 0.f);
}

// sx = relu(b + agg@Wrel(64x64) + state@Wroot(6x64))
__global__ __launch_bounds__(256, 4)
void k_gc_w(const float* __restrict__ agg, const float* __restrict__ st,
            const float* __restrict__ Wrel, const float* __restrict__ Wroot,
            const float* __restrict__ b, float* __restrict__ out, int n) {
    int wv = (int)(((long long)blockIdx.x * blockDim.x + threadIdx.x) >> 6);
    int lane = threadIdx.x & 63;
    int i0 = wv * 4;
    if (i0 >= n) return;
    float xs[4], sr[4], acc[4];
    #pragma unroll
    for (int r = 0; r < 4; r++) {
        int i = (i0 + r < n) ? i0 + r : n - 1;
        xs[r] = agg[(size_t)i * 64 + lane];
        sr[r] = (lane < 6) ? st[(size_t)i * 6 + lane] : 0.f;
        acc[r] = b[lane];
    }
    #pragma unroll 8
    for (int k = 0; k < 64; k++) {
        float wk = Wrel[k * 64 + lane];
        #pragma unroll
        for (int r = 0; r < 4; r++) acc[r] += bcast(xs[r], k) * wk;
    }
    #pragma unroll
    for (int k = 0; k < 6; k++) {
        float wk = Wroot[k * 64 + lane];
        #pragma unroll
        for (int r = 0; r < 4; r++) acc[r] += bcast(sr[r], k) * wk;
    }
    #pragma unroll
    for (int r = 0; r < 4; r++)
        if (i0 + r < n) out[(size_t)(i0 + r) * 64 + lane] = fmaxf(acc[r], 0.f);
}

// sx2 = relu(bl + (ssum/max(cnt,1))@Wl + sx@Wr); cnt from rowptr diff
__global__ __launch_bounds__(256, 4)
void k_sage_w(const float* __restrict__ ssum, const int* __restrict__ rp,
              const float* __restrict__ sx, const float* __restrict__ Wl,
              const float* __restrict__ Wr, const float* __restrict__ bl,
              float* __restrict__ out, int n) {
    int wv = (int)(((long long)blockIdx.x * blockDim.x + threadIdx.x) >> 6);
    int lane = threadIdx.x & 63;
    int i0 = wv * 4;
    if (i0 >= n) return;
    float xs[4], ys[4], acc[4];
    #pragma unroll
    for (int r = 0; r < 4; r++) {
        int i = (i0 + r < n) ? i0 + r : n - 1;
        float cnt = (float)(rp[i + 1] - rp[i]);
        float rs = 1.f / fmaxf(cnt, 1.f);
        xs[r] = ssum[(size_t)i * 64 + lane] * rs;
        ys[r] = sx[(size_t)i * 64 + lane];
        acc[r] = bl[lane];
    }
    #pragma unroll 8
    for (int k = 0; k < 64; k++) {
        float wl = Wl[k * 64 + lane];
        float wr = Wr[k * 64 + lane];
        #pragma unroll
        for (int r = 0; r < 4; r++)
            acc[r] += bcast(xs[r], k) * wl + bcast(ys[r], k) * wr;
    }
    #pragma unroll
    for (int r = 0; r < 4; r++)
        if (i0 + r < n) out[(size_t)(i0 + r) * 64 + lane] = fmaxf(acc[r], 0.f);
}

// INIT: out = bias + x@W ; else: out += x@W   (W 64x64)
template<bool INIT>
__global__ __launch_bounds__(256, 4)
void k_mm_w(const float* __restrict__ x, const float* __restrict__ W,
            const float* __restrict__ bias, float* __restrict__ out, int n) {
    int wv = (int)(((long long)blockIdx.x * blockDim.x + threadIdx.x) >> 6);
    int lane = threadIdx.x & 63;
    int i0 = wv * 4;
    if (i0 >= n) return;
    float xs[4], acc[4];
    #pragma unroll
    for (int r = 0; r < 4; r++) {
        int i = (i0 + r < n) ? i0 + r : n - 1;
        xs[r] = x[(size_t)i * 64 + lane];
        acc[r] = INIT ? bias[lane] : out[(size_t)i * 64 + lane];
    }
    #pragma unroll 8
    for (int k = 0; k < 64; k++) {
        float wk = W[k * 64 + lane];
        #pragma unroll
        for (int r = 0; r < 4; r++) acc[r] += bcast(xs[r], k) * wk;
    }
    #pragma unroll
    for (int r = 0; r < 4; r++)
        if (i0 + r < n) out[(size_t)(i0 + r) * 64 + lane] = acc[r];
}

// out = relu(sx3) @ lin_W + lin_b  (64 -> 8)
__global__ void k_final(const float* __restrict__ x, const float* __restrict__ W,
                        const float* __restrict__ b, float* __restrict__ out, int n) {
    int t = blockIdx.x * blockDim.x + threadIdx.x;
    if (t >= n * 8) return;
    int i = t >> 3, o = t & 7;
    float acc = b[o];
    #pragma unroll 8
    for (int k = 0; k < 64; k++) acc += fmaxf(x[i * 64 + k], 0.f) * W[k * 8 + o];
    out[t] = acc;
}

static inline unsigned gblk(long long n) { return (unsigned)((n + BLK - 1) / BLK); }
static inline unsigned gwv4(long long n) { return gblk(((n + 3) / 4) * 64); }

static void build_csr_base(const int* dst, int E, int N,
                           int* rowptr, int* cursor, int* bsum, float* dinv,
                           hipStream_t stream) {
    hipMemsetAsync(cursor, 0, (size_t)N * sizeof(int), stream);
    k_hist<<<gblk(E), BLK, 0, stream>>>(dst, cursor, E);
    int nb = (N + 255) / 256;
    k_scan_block<<<nb, 256, 0, stream>>>(cursor, rowptr, bsum, dinv, N);
    k_scan_top<<<1, 1024, 0, stream>>>(bsum, nb);
    k_scan_add<<<gblk(N), BLK, 0, stream>>>(rowptr, bsum, cursor, N, E);
}

extern "C" void kernel_launch(void* const* d_in, const int* in_sizes, int n_in,
                              void* d_out, int out_size, void* d_ws, size_t ws_size,
                              hipStream_t stream) {
    const float* game_x  = (const float*)d_in[0];
    const float* state_x = (const float*)d_in[1];
    const int*   ei_vv   = (const int*)d_in[2];
    const int*   ei_h    = (const int*)d_in[3];
    const float* ea_h    = (const float*)d_in[4];
    const int*   ei_in   = (const int*)d_in[5];
    const int*   ei_ss   = (const int*)d_in[6];
    const float* tag1_W  = (const float*)d_in[7];
    const float* tag1_b  = (const float*)d_in[8];
    const float* tag2_W  = (const float*)d_in[9];
    const float* tag2_b  = (const float*)d_in[10];
    const float* gc_Wrel = (const float*)d_in[11];
    const float* gc_b    = (const float*)d_in[12];
    const float* gc_Wroot= (const float*)d_in[13];
    const float* sage_Wl = (const float*)d_in[14];
    const float* sage_bl = (const float*)d_in[15];
    const float* sage_Wr = (const float*)d_in[16];
    const float* lin_W   = (const float*)d_in[17];
    const float* lin_b   = (const float*)d_in[18];

    const int NV  = in_sizes[0] / 5;
    const int NS  = in_sizes[1] / 6;
    const int EVV = in_sizes[2] / 2;
    const int EH  = in_sizes[3] / 2;
    const int EIN = in_sizes[5] / 2;
    const int ESS = in_sizes[6] / 2;

    const int *vv_s = ei_vv,  *vv_d = ei_vv + EVV;
    const int *h_s  = ei_h,   *h_d  = ei_h  + EH;
    const int *in_s = ei_in,  *in_d = ei_in + EIN;
    const int *ss_s = ei_ss,  *ss_d = ei_ss + ESS;

    // ---------------- workspace layout (4-byte words) ----------------
    float* wsf = (float*)d_ws;
    size_t o = 0;
    float* gx   = wsf + o; o += (size_t)NV * 64;                        // sx3 reuses this
    float* B1   = wsf + o; o += (size_t)NS * 64 + ((size_t)NS * 2 + (size_t)EIN + 64); // agg | (inCSR+ssum) | hA
    float* B2   = wsf + o; o += (size_t)NS * 64;                        // sx | hB
    float* B4   = wsf + o; o += (size_t)NS * 64;                        // h1v+h2v | hCSR | sx2
    float* pool = wsf + o; o += (size_t)NV + (size_t)NV + (size_t)EVV + 64; // vv CSR | ss CSR
    float* dinv = wsf + o; o += (size_t)NV;                             // dinv_v | dinv_s
    int*   bsum = (int*)(wsf + o); o += 1024;

    // ================= Stage A: TAGConv1 on v-v =================
    int* vvrp  = (int*)pool;
    int* vvcur = vvrp + NV + 1;
    int* vvsrc = vvcur + NV;
    build_csr_base(vv_d, EVV, NV, vvrp, vvcur, bsum, dinv, stream);
    k_fill<<<gblk(EVV), BLK, 0, stream>>>(vv_s, vv_d, vvcur, vvsrc, EVV);

    float* h1v = B4;
    float* h2v = B4 + (size_t)NV * 5;
    k_gather5<<<gblk(NV), BLK, 0, stream>>>(game_x, vvrp, vvsrc, dinv, h1v, NV);
    k_gather5<<<gblk(NV), BLK, 0, stream>>>(h1v,    vvrp, vvsrc, dinv, h2v, NV);
    k_tag1_w<<<gwv4(NV), BLK, 0, stream>>>(game_x, h1v, h2v, tag1_W, tag1_b, gx, NV);

    // ================= Stage B: GraphConv (weighted) =================
    int*   hrp  = (int*)B4;                 // h1v/h2v dead
    int*   hcur = hrp + NS + 1;
    int*   hsrc = hcur + NS;
    float* hw   = (float*)(hsrc + EH);
    build_csr_base(h_d, EH, NS, hrp, hcur, bsum, nullptr, stream);
    k_fill_w<<<gblk(EH), BLK, 0, stream>>>(h_s, h_d, ea_h, hcur, hsrc, hw, EH);

    float* agg = B1;
    float* sx  = B2;
    k_gather64<1><<<gblk((long long)NS * 64), BLK, 0, stream>>>(gx, hrp, hsrc, hw, nullptr, agg, NS);
    k_gc_w<<<gwv4(NS), BLK, 0, stream>>>(agg, state_x, gc_Wrel, gc_Wroot, gc_b, sx, NS);

    // ================= Stage C: SAGE mean =================
    int*   inrp  = (int*)B1;                // agg dead
    int*   incur = inrp + NS + 1;
    int*   insrc = incur + NS;
    float* ssum  = B1 + ((size_t)NS * 2 + (size_t)EIN + 32);
    build_csr_base(in_d, EIN, NS, inrp, incur, bsum, nullptr, stream);
    k_fill<<<gblk(EIN), BLK, 0, stream>>>(in_s, in_d, incur, insrc, EIN);
    k_gather64<0><<<gblk((long long)NS * 64), BLK, 0, stream>>>(gx, inrp, insrc, nullptr, nullptr, ssum, NS);

    float* sx2 = B4;                        // h CSR dead
    k_sage_w<<<gwv4(NS), BLK, 0, stream>>>(ssum, inrp, sx, sage_Wl, sage_Wr, sage_bl, sx2, NS);

    // ================= Stage D: TAGConv2 on s-s (K=3) =================
    int* ssrp  = (int*)pool;                // vv CSR dead
    int* sscur = ssrp + NS + 1;
    int* sssrc = sscur + NS;
    build_csr_base(ss_d, ESS, NS, ssrp, sscur, bsum, dinv, stream);  // dinv_v dead -> dinv_s
    k_fill<<<gblk(ESS), BLK, 0, stream>>>(ss_s, ss_d, sscur, sssrc, ESS);

    float* sx3 = gx;                        // gx dead after stage C gather
    float* hA  = B1;                        // in CSR + ssum dead
    float* hB  = B2;                        // sx dead

    k_mm_w<true><<<gwv4(NS), BLK, 0, stream>>>(sx2, tag2_W, tag2_b, sx3, NS);
    k_gather64<2><<<gblk((long long)NS * 64), BLK, 0, stream>>>(sx2, ssrp, sssrc, nullptr, dinv, hA, NS);
    k_mm_w<false><<<gwv4(NS), BLK, 0, stream>>>(hA, tag2_W + 4096, nullptr, sx3, NS);
    k_gather64<2><<<gblk((long long)NS * 64), BLK, 0, stream>>>(hA, ssrp, sssrc, nullptr, dinv, hB, NS);
    k_mm_w<false><<<gwv4(NS), BLK, 0, stream>>>(hB, tag2_W + 8192, nullptr, sx3, NS);
    k_gather64<2><<<gblk((long long)NS * 64), BLK, 0, stream>>>(hB, ssrp, sssrc, nullptr, dinv, hA, NS);
    k_mm_w<false><<<gwv4(NS), BLK, 0, stream>>>(hA, tag2_W + 12288, nullptr, sx3, NS);

    // ================= Stage E: final linear (relu fused) =================
    k_final<<<gblk((long long)NS * 8), BLK, 0, stream>>>(sx3, lin_W, lin_b, (float*)d_out, NS);
}

// Round 6
// 839.883 us; speedup vs baseline: 2.4857x; 1.0955x over previous
//
#include <hip/hip_runtime.h>

#define BLK 256

// broadcast lane l of v across the wave (l wave-uniform; dynamic is legal)
__device__ __forceinline__ float bcast(float v, int l) {
    return __int_as_float(__builtin_amdgcn_readlane(__float_as_int(v), l));
}

// ================= batched CSR skeleton (all 4 graphs) =================

// one dispatch: histogram all 4 graphs' dst lists
__global__ void k_hist_all(const int* __restrict__ dv, const int* __restrict__ dh,
                           const int* __restrict__ di, const int* __restrict__ ds,
                           int* __restrict__ cv, int* __restrict__ ch,
                           int* __restrict__ ci, int* __restrict__ cs,
                           int Ev, int Eh, int Ei, int Es) {
    int e = blockIdx.x * blockDim.x + threadIdx.x;
    if (e < Ev) { atomicAdd(&cv[dv[e]], 1); return; }
    e -= Ev;
    if (e < Eh) { atomicAdd(&ch[dh[e]], 1); return; }
    e -= Eh;
    if (e < Ei) { atomicAdd(&ci[di[e]], 1); return; }
    e -= Ei;
    if (e < Es) atomicAdd(&cs[ds[e]], 1);
}

// batched per-256-block exclusive scan; also emits dinv=rsqrt(deg) for vv/ss
__global__ void k_scanb_all(const int* __restrict__ cv, const int* __restrict__ ch,
                            const int* __restrict__ ci, const int* __restrict__ cs,
                            int* __restrict__ rv, int* __restrict__ rh,
                            int* __restrict__ ri, int* __restrict__ rs,
                            float* __restrict__ dv, float* __restrict__ ds,
                            int* __restrict__ bsum, int nv, int ns, int nbv, int nbs) {
    __shared__ int sh[256];
    int blk = blockIdx.x;
    const int* cnt; int* rp; float* dinv; int n; int lb;
    if (blk < nbv)                { cnt = cv; rp = rv; dinv = dv;     n = nv; lb = blk; }
    else if (blk < nbv + nbs)     { cnt = ch; rp = rh; dinv = nullptr; n = ns; lb = blk - nbv; }
    else if (blk < nbv + 2 * nbs) { cnt = ci; rp = ri; dinv = nullptr; n = ns; lb = blk - nbv - nbs; }
    else                          { cnt = cs; rp = rs; dinv = ds;     n = ns; lb = blk - nbv - 2 * nbs; }
    int i = lb * 256 + threadIdx.x;
    int v = (i < n) ? cnt[i] : 0;
    if (dinv && i < n) dinv[i] = v > 0 ? rsqrtf((float)v) : 0.f;
    sh[threadIdx.x] = v; __syncthreads();
    for (int off = 1; off < 256; off <<= 1) {
        int t = (threadIdx.x >= off) ? sh[threadIdx.x - off] : 0;
        __syncthreads();
        sh[threadIdx.x] += t; __syncthreads();
    }
    if (i < n) rp[i] = sh[threadIdx.x] - v;
    if (threadIdx.x == 255) bsum[blk] = sh[255];
}

// segmented top scan: block g scans graph g's block sums in place
__global__ void k_scant_all(int* __restrict__ bsum, int nbv, int nbs) {
    __shared__ int sh[1024];
    int g = blockIdx.x;
    int off = (g == 0) ? 0 : nbv + (g - 1) * nbs;
    int nb  = (g == 0) ? nbv : nbs;
    int tid = threadIdx.x;
    int v = (tid < nb) ? bsum[off + tid] : 0;
    sh[tid] = v; __syncthreads();
    for (int o2 = 1; o2 < 1024; o2 <<= 1) {
        int t = (tid >= o2) ? sh[tid - o2] : 0;
        __syncthreads();
        sh[tid] += t; __syncthreads();
    }
    if (tid < nb) bsum[off + tid] = sh[tid] - v;
}

// finalize rowptrs, init cursors, set rp[n]=E (batched, same mapping as scanb)
__global__ void k_scana_all(int* __restrict__ rv, int* __restrict__ rh,
                            int* __restrict__ ri, int* __restrict__ rs,
                            int* __restrict__ cv, int* __restrict__ ch,
                            int* __restrict__ ci, int* __restrict__ cs,
                            const int* __restrict__ bsum, int nv, int ns, int nbv, int nbs,
                            int Ev, int Eh, int Ei, int Es) {
    int blk = blockIdx.x;
    int* rp; int* cur; int n; int lb; int E;
    if (blk < nbv)                { rp = rv; cur = cv; n = nv; lb = blk;               E = Ev; }
    else if (blk < nbv + nbs)     { rp = rh; cur = ch; n = ns; lb = blk - nbv;         E = Eh; }
    else if (blk < nbv + 2 * nbs) { rp = ri; cur = ci; n = ns; lb = blk - nbv - nbs;   E = Ei; }
    else                          { rp = rs; cur = cs; n = ns; lb = blk - nbv - 2*nbs; E = Es; }
    int i = lb * 256 + threadIdx.x;
    if (i < n) { int r = rp[i] + bsum[blk]; rp[i] = r; cur[i] = r; }
    if (i == 0) rp[n] = E;
}

__global__ void k_fill(const int* __restrict__ src, const int* __restrict__ dst,
                       int* __restrict__ cursor, int* __restrict__ csr_src, int E) {
    int e = blockIdx.x * blockDim.x + threadIdx.x;
    if (e >= E) return;
    int p = atomicAdd(&cursor[dst[e]], 1);
    csr_src[p] = src[e];
}

// packed: one 8B store (src, weight-bits) per edge instead of two 4B stores
__global__ void k_fill_w8(const int* __restrict__ src, const int* __restrict__ dst,
                          const float* __restrict__ w, int* __restrict__ cursor,
                          int2* __restrict__ csr_sw, int E) {
    int e = blockIdx.x * blockDim.x + threadIdx.x;
    if (e >= E) return;
    int p = atomicAdd(&cursor[dst[e]], 1);
    csr_sw[p] = make_int2(src[e], __float_as_int(w[e]));
}

// ================= gathers =================

__global__ void k_gather5(const float* __restrict__ x, const int* __restrict__ rowptr,
                          const int* __restrict__ csr_src, const float* __restrict__ dinv,
                          float* __restrict__ out, int n) {
    int d = blockIdx.x * blockDim.x + threadIdx.x;
    if (d >= n) return;
    int b = rowptr[d], e = rowptr[d + 1];
    float dd = dinv[d];
    float a0 = 0, a1 = 0, a2 = 0, a3 = 0, a4 = 0;
    int p = b;
    for (; p + 4 <= e; p += 4) {
        int s0 = csr_src[p], s1 = csr_src[p+1], s2 = csr_src[p+2], s3 = csr_src[p+3];
        const float* x0 = x + (size_t)s0 * 5;
        const float* x1 = x + (size_t)s1 * 5;
        const float* x2 = x + (size_t)s2 * 5;
        const float* x3 = x + (size_t)s3 * 5;
        float w0 = dd * dinv[s0], w1 = dd * dinv[s1], w2 = dd * dinv[s2], w3 = dd * dinv[s3];
        a0 += x0[0]*w0 + x1[0]*w1 + x2[0]*w2 + x3[0]*w3;
        a1 += x0[1]*w0 + x1[1]*w1 + x2[1]*w2 + x3[1]*w3;
        a2 += x0[2]*w0 + x1[2]*w1 + x2[2]*w2 + x3[2]*w3;
        a3 += x0[3]*w0 + x1[3]*w1 + x2[3]*w2 + x3[3]*w3;
        a4 += x0[4]*w0 + x1[4]*w1 + x2[4]*w2 + x3[4]*w3;
    }
    for (; p < e; p++) {
        int s = csr_src[p];
        float w = dd * dinv[s];
        const float* xp = x + (size_t)s * 5;
        a0 += xp[0]*w; a1 += xp[1]*w; a2 += xp[2]*w; a3 += xp[3]*w; a4 += xp[4]*w;
    }
    float* op = out + (size_t)d * 5;
    op[0] = a0; op[1] = a1; op[2] = a2; op[3] = a3; op[4] = a4;
}

// 64-channel gather: wave per dst row; 4 groups x 16 lanes x float4; 2-edge unroll
// MODE: 0 = plain sum (csr_src), 1 = per-edge weight (int2 packed), 2 = gcn norm (csr_src)
template<int MODE>
__global__ void k_gather64(const float* __restrict__ x, const int* __restrict__ rowptr,
                           const int* __restrict__ csr_src, const int2* __restrict__ csr_sw,
                           const float* __restrict__ dinv, float* __restrict__ out, int n) {
    int wid = (int)(((long long)blockIdx.x * blockDim.x + threadIdx.x) >> 6);
    if (wid >= n) return;
    int lane = threadIdx.x & 63;
    int g = lane >> 4, q = lane & 15;
    int b = rowptr[wid], e = rowptr[wid + 1];
    float dd = (MODE == 2) ? dinv[wid] : 0.f;
    float4 a0 = make_float4(0.f,0.f,0.f,0.f), a1 = make_float4(0.f,0.f,0.f,0.f);
    int p = b + g;
    for (; p + 4 < e; p += 8) {
        int sA, sB; float wA = 1.f, wB = 1.f;
        if (MODE == 1) {
            int2 eA = csr_sw[p], eB = csr_sw[p + 4];
            sA = eA.x; wA = __int_as_float(eA.y);
            sB = eB.x; wB = __int_as_float(eB.y);
        } else {
            sA = csr_src[p]; sB = csr_src[p + 4];
            if (MODE == 2) { wA = dd * dinv[sA]; wB = dd * dinv[sB]; }
        }
        float4 vA = ((const float4*)(x + (size_t)sA * 64))[q];
        float4 vB = ((const float4*)(x + (size_t)sB * 64))[q];
        if (MODE == 0) {
            a0.x += vA.x; a0.y += vA.y; a0.z += vA.z; a0.w += vA.w;
            a1.x += vB.x; a1.y += vB.y; a1.z += vB.z; a1.w += vB.w;
        } else {
            a0.x += vA.x * wA; a0.y += vA.y * wA; a0.z += vA.z * wA; a0.w += vA.w * wA;
            a1.x += vB.x * wB; a1.y += vB.y * wB; a1.z += vB.z * wB; a1.w += vB.w * wB;
        }
    }
    if (p < e) {
        int s; float w = 1.f;
        if (MODE == 1) { int2 eA = csr_sw[p]; s = eA.x; w = __int_as_float(eA.y); }
        else { s = csr_src[p]; if (MODE == 2) w = dd * dinv[s]; }
        float4 v = ((const float4*)(x + (size_t)s * 64))[q];
        if (MODE == 0) { a0.x += v.x; a0.y += v.y; a0.z += v.z; a0.w += v.w; }
        else { a0.x += v.x * w; a0.y += v.y * w; a0.z += v.z * w; a0.w += v.w * w; }
    }
    a0.x += a1.x; a0.y += a1.y; a0.z += a1.z; a0.w += a1.w;
    #pragma unroll
    for (int off = 16; off < 64; off <<= 1) {
        a0.x += __shfl_xor(a0.x, off, 64);
        a0.y += __shfl_xor(a0.y, off, 64);
        a0.z += __shfl_xor(a0.z, off, 64);
        a0.w += __shfl_xor(a0.w, off, 64);
    }
    if (g == 0) ((float4*)(out + (size_t)wid * 64))[q] = a0;
}

// ================= dense combines (wave-tiled register GEMMs) =================

__global__ __launch_bounds__(256, 4)
void k_tag1_w(const float* __restrict__ x, const float* __restrict__ h1,
              const float* __restrict__ h2, const float* __restrict__ W,
              const float* __restrict__ b, float* __restrict__ out, int n) {
    int wv = (int)(((long long)blockIdx.x * blockDim.x + threadIdx.x) >> 6);
    int lane = threadIdx.x & 63;
    int i0 = wv * 4;
    if (i0 >= n) return;
    float v[4], acc[4];
    #pragma unroll
    for (int r = 0; r < 4; r++) {
        int i = (i0 + r < n) ? i0 + r : n - 1;
        float t = 0.f;
        if (lane < 5)                     t = x [(size_t)i * 5 + lane];
        else if (lane >= 8 && lane < 13)  t = h1[(size_t)i * 5 + lane - 8];
        else if (lane >= 16 && lane < 21) t = h2[(size_t)i * 5 + lane - 16];
        v[r] = t;
        acc[r] = b[lane];
    }
    #pragma unroll
    for (int m = 0; m < 3; m++) {
        #pragma unroll
        for (int k = 0; k < 5; k++) {
            float wk = W[(m * 5 + k) * 64 + lane];
            #pragma unroll
            for (int r = 0; r < 4; r++) acc[r] += bcast(v[r], m * 8 + k) * wk;
        }
    }
    #pragma unroll
    for (int r = 0; r < 4; r++)
        if (i0 + r < n) out[(size_t)(i0 + r) * 64 + lane] = fmaxf(acc[r], 0.f);
}

__global__ __launch_bounds__(256, 4)
void k_gc_w(const float* __restrict__ agg, const float* __restrict__ st,
            const float* __restrict__ Wrel, const float* __restrict__ Wroot,
            const float* __restrict__ b, float* __restrict__ out, int n) {
    int wv = (int)(((long long)blockIdx.x * blockDim.x + threadIdx.x) >> 6);
    int lane = threadIdx.x & 63;
    int i0 = wv * 4;
    if (i0 >= n) return;
    float xs[4], sr[4], acc[4];
    #pragma unroll
    for (int r = 0; r < 4; r++) {
        int i = (i0 + r < n) ? i0 + r : n - 1;
        xs[r] = agg[(size_t)i * 64 + lane];
        sr[r] = (lane < 6) ? st[(size_t)i * 6 + lane] : 0.f;
        acc[r] = b[lane];
    }
    #pragma unroll 8
    for (int k = 0; k < 64; k++) {
        float wk = Wrel[k * 64 + lane];
        #pragma unroll
        for (int r = 0; r < 4; r++) acc[r] += bcast(xs[r], k) * wk;
    }
    #pragma unroll
    for (int k = 0; k < 6; k++) {
        float wk = Wroot[k * 64 + lane];
        #pragma unroll
        for (int r = 0; r < 4; r++) acc[r] += bcast(sr[r], k) * wk;
    }
    #pragma unroll
    for (int r = 0; r < 4; r++)
        if (i0 + r < n) out[(size_t)(i0 + r) * 64 + lane] = fmaxf(acc[r], 0.f);
}

__global__ __launch_bounds__(256, 4)
void k_sage_w(const float* __restrict__ ssum, const int* __restrict__ rp,
              const float* __restrict__ sx, const float* __restrict__ Wl,
              const float* __restrict__ Wr, const float* __restrict__ bl,
              float* __restrict__ out, int n) {
    int wv = (int)(((long long)blockIdx.x * blockDim.x + threadIdx.x) >> 6);
    int lane = threadIdx.x & 63;
    int i0 = wv * 4;
    if (i0 >= n) return;
    float xs[4], ys[4], acc[4];
    #pragma unroll
    for (int r = 0; r < 4; r++) {
        int i = (i0 + r < n) ? i0 + r : n - 1;
        float cnt = (float)(rp[i + 1] - rp[i]);
        float rs = 1.f / fmaxf(cnt, 1.f);
        xs[r] = ssum[(size_t)i * 64 + lane] * rs;
        ys[r] = sx[(size_t)i * 64 + lane];
        acc[r] = bl[lane];
    }
    #pragma unroll 8
    for (int k = 0; k < 64; k++) {
        float wl = Wl[k * 64 + lane];
        float wr = Wr[k * 64 + lane];
        #pragma unroll
        for (int r = 0; r < 4; r++)
            acc[r] += bcast(xs[r], k) * wl + bcast(ys[r], k) * wr;
    }
    #pragma unroll
    for (int r = 0; r < 4; r++)
        if (i0 + r < n) out[(size_t)(i0 + r) * 64 + lane] = fmaxf(acc[r], 0.f);
}

template<bool INIT>
__global__ __launch_bounds__(256, 4)
void k_mm_w(const float* __restrict__ x, const float* __restrict__ W,
            const float* __restrict__ bias, float* __restrict__ out, int n) {
    int wv = (int)(((long long)blockIdx.x * blockDim.x + threadIdx.x) >> 6);
    int lane = threadIdx.x & 63;
    int i0 = wv * 4;
    if (i0 >= n) return;
    float xs[4], acc[4];
    #pragma unroll
    for (int r = 0; r < 4; r++) {
        int i = (i0 + r < n) ? i0 + r : n - 1;
        xs[r] = x[(size_t)i * 64 + lane];
        acc[r] = INIT ? bias[lane] : out[(size_t)i * 64 + lane];
    }
    #pragma unroll 8
    for (int k = 0; k < 64; k++) {
        float wk = W[k * 64 + lane];
        #pragma unroll
        for (int r = 0; r < 4; r++) acc[r] += bcast(xs[r], k) * wk;
    }
    #pragma unroll
    for (int r = 0; r < 4; r++)
        if (i0 + r < n) out[(size_t)(i0 + r) * 64 + lane] = acc[r];
}

__global__ void k_final(const float* __restrict__ x, const float* __restrict__ W,
                        const float* __restrict__ b, float* __restrict__ out, int n) {
    int t = blockIdx.x * blockDim.x + threadIdx.x;
    if (t >= n * 8) return;
    int i = t >> 3, o = t & 7;
    float acc = b[o];
    #pragma unroll 8
    for (int k = 0; k < 64; k++) acc += fmaxf(x[i * 64 + k], 0.f) * W[k * 8 + o];
    out[t] = acc;
}

static inline unsigned gblk(long long n) { return (unsigned)((n + BLK - 1) / BLK); }
static inline unsigned gwv4(long long n) { return gblk(((n + 3) / 4) * 64); }

extern "C" void kernel_launch(void* const* d_in, const int* in_sizes, int n_in,
                              void* d_out, int out_size, void* d_ws, size_t ws_size,
                              hipStream_t stream) {
    const float* game_x  = (const float*)d_in[0];
    const float* state_x = (const float*)d_in[1];
    const int*   ei_vv   = (const int*)d_in[2];
    const int*   ei_h    = (const int*)d_in[3];
    const float* ea_h    = (const float*)d_in[4];
    const int*   ei_in   = (const int*)d_in[5];
    const int*   ei_ss   = (const int*)d_in[6];
    const float* tag1_W  = (const float*)d_in[7];
    const float* tag1_b  = (const float*)d_in[8];
    const float* tag2_W  = (const float*)d_in[9];
    const float* tag2_b  = (const float*)d_in[10];
    const float* gc_Wrel = (const float*)d_in[11];
    const float* gc_b    = (const float*)d_in[12];
    const float* gc_Wroot= (const float*)d_in[13];
    const float* sage_Wl = (const float*)d_in[14];
    const float* sage_bl = (const float*)d_in[15];
    const float* sage_Wr = (const float*)d_in[16];
    const float* lin_W   = (const float*)d_in[17];
    const float* lin_b   = (const float*)d_in[18];

    const int NV  = in_sizes[0] / 5;
    const int NS  = in_sizes[1] / 6;
    const int EVV = in_sizes[2] / 2;
    const int EH  = in_sizes[3] / 2;
    const int EIN = in_sizes[5] / 2;
    const int ESS = in_sizes[6] / 2;

    const int *vv_s = ei_vv,  *vv_d = ei_vv + EVV;
    const int *h_s  = ei_h,   *h_d  = ei_h  + EH;
    const int *in_s = ei_in,  *in_d = ei_in + EIN;
    const int *ss_s = ei_ss,  *ss_d = ei_ss + ESS;

    // ---------------- workspace layout (4-byte words) ----------------
    float* wsf = (float*)d_ws;
    size_t o = 0;
    float* gx = wsf + o; o += (size_t)NV * 64;                 // gx | sx3
    float* B1 = wsf + o; o += (size_t)EIN + 64 + (size_t)NS * 64; // agg | insrc+ssum | hA
    float* B2 = wsf + o; o += (size_t)NS * 64;                 // sx | hB
    float* B4 = wsf + o; o += (size_t)NS * 64;                 // h1v+h2v | hsrc8 | sx2
    int*   vs = (int*)(wsf + o); o += (size_t)(EVV > ESS ? EVV : ESS); // vvsrc | sssrc
    // small CSR-skeleton pool (persists whole call)
    int* cv = (int*)(wsf + o);
    int* ch = cv + NV;
    int* ci = ch + NS;
    int* cs = ci + NS;
    int* rv = cs + NS;            // NV+1
    int* rh = rv + NV + 1;        // NS+1
    int* ri = rh + NS + 1;        // NS+1
    int* rs = ri + NS + 1;        // NS+1
    float* dinv_v = (float*)(rs + NS + 1);  // NV
    float* dinv_s = dinv_v + NV;            // NS
    int* bsum = (int*)(dinv_s + NS);        // up to 1024

    float* ssum = B1 + (size_t)EIN + 64;

    // ================= Phase 0: batched CSR skeleton =================
    hipMemsetAsync(cv, 0, (size_t)(NV + 3 * NS) * sizeof(int), stream);
    long long Etot = (long long)EVV + EH + EIN + ESS;
    k_hist_all<<<gblk(Etot), BLK, 0, stream>>>(vv_d, h_d, in_d, ss_d, cv, ch, ci, cs,
                                               EVV, EH, EIN, ESS);
    int nbv = (NV + 255) / 256, nbs = (NS + 255) / 256;
    int NB = nbv + 3 * nbs;
    k_scanb_all<<<NB, 256, 0, stream>>>(cv, ch, ci, cs, rv, rh, ri, rs,
                                        dinv_v, dinv_s, bsum, NV, NS, nbv, nbs);
    k_scant_all<<<4, 1024, 0, stream>>>(bsum, nbv, nbs);
    k_scana_all<<<NB, 256, 0, stream>>>(rv, rh, ri, rs, cv, ch, ci, cs, bsum,
                                        NV, NS, nbv, nbs, EVV, EH, EIN, ESS);

    // ================= Stage A: TAGConv1 on v-v =================
    k_fill<<<gblk(EVV), BLK, 0, stream>>>(vv_s, vv_d, cv, vs, EVV);
    float* h1v = B4;
    float* h2v = B4 + (size_t)NV * 5;
    k_gather5<<<gblk(NV), BLK, 0, stream>>>(game_x, rv, vs, dinv_v, h1v, NV);
    k_gather5<<<gblk(NV), BLK, 0, stream>>>(h1v,    rv, vs, dinv_v, h2v, NV);
    k_tag1_w<<<gwv4(NV), BLK, 0, stream>>>(game_x, h1v, h2v, tag1_W, tag1_b, gx, NV);

    // ================= Stage B: GraphConv (weighted) =================
    int2* hsw = (int2*)B4;   // h1v/h2v dead
    k_fill_w8<<<gblk(EH), BLK, 0, stream>>>(h_s, h_d, ea_h, ch, hsw, EH);
    k_gather64<1><<<gblk((long long)NS * 64), BLK, 0, stream>>>(gx, rh, nullptr, hsw, nullptr, B1, NS);
    k_gc_w<<<gwv4(NS), BLK, 0, stream>>>(B1, state_x, gc_Wrel, gc_Wroot, gc_b, B2, NS);

    // ================= Stage C: SAGE mean =================
    int* insrc = (int*)B1;   // agg dead
    k_fill<<<gblk(EIN), BLK, 0, stream>>>(in_s, in_d, ci, insrc, EIN);
    k_gather64<0><<<gblk((long long)NS * 64), BLK, 0, stream>>>(gx, ri, insrc, nullptr, nullptr, ssum, NS);
    float* sx2 = B4;         // hsrc8 dead
    k_sage_w<<<gwv4(NS), BLK, 0, stream>>>(ssum, ri, B2, sage_Wl, sage_Wr, sage_bl, sx2, NS);

    // ================= Stage D: TAGConv2 on s-s (K=3) =================
    k_fill<<<gblk(ESS), BLK, 0, stream>>>(ss_s, ss_d, cs, vs, ESS);  // vvsrc dead
    float* sx3 = gx;         // gx dead after stage-C gather
    float* hA  = B1;         // insrc+ssum dead after sage
    float* hB  = B2;         // sx dead after sage

    k_mm_w<true><<<gwv4(NS), BLK, 0, stream>>>(sx2, tag2_W, tag2_b, sx3, NS);
    k_gather64<2><<<gblk((long long)NS * 64), BLK, 0, stream>>>(sx2, rs, vs, nullptr, dinv_s, hA, NS);
    k_mm_w<false><<<gwv4(NS), BLK, 0, stream>>>(hA, tag2_W + 4096, nullptr, sx3, NS);
    k_gather64<2><<<gblk((long long)NS * 64), BLK, 0, stream>>>(hA, rs, vs, nullptr, dinv_s, hB, NS);
    k_mm_w<false><<<gwv4(NS), BLK, 0, stream>>>(hB, tag2_W + 8192, nullptr, sx3, NS);
    k_gather64<2><<<gblk((long long)NS * 64), BLK, 0, stream>>>(hB, rs, vs, nullptr, dinv_s, hA, NS);
    k_mm_w<false><<<gwv4(NS), BLK, 0, stream>>>(hA, tag2_W + 12288, nullptr, sx3, NS);

    // ================= Stage E: final linear (relu fused) =================
    k_final<<<gblk((long long)NS * 8), BLK, 0, stream>>>(sx3, lin_W, lin_b, (float*)d_out, NS);
}

// Round 7
// 665.832 us; speedup vs baseline: 3.1355x; 1.2614x over previous
//
#include <hip/hip_runtime.h>

#define BLK 256

// broadcast lane l of v across the wave (l wave-uniform; dynamic is legal)
__device__ __forceinline__ float bcast(float v, int l) {
    return __int_as_float(__builtin_amdgcn_readlane(__float_as_int(v), l));
}

// ================= batched CSR skeleton (all 4 graphs) =================
// hist returns each edge's rank within its dst (ushort, deg << 65536) so the
// fill kernels need NO atomics: slot = rowptr[dst] + rank.

__global__ void k_hist_all(const int* __restrict__ dv, const int* __restrict__ dh,
                           const int* __restrict__ di, const int* __restrict__ ds,
                           int* __restrict__ cv, int* __restrict__ ch,
                           int* __restrict__ ci, int* __restrict__ cs,
                           unsigned short* __restrict__ rkv, unsigned short* __restrict__ rkh,
                           unsigned short* __restrict__ rki, unsigned short* __restrict__ rks,
                           int Ev, int Eh, int Ei, int Es) {
    int e = blockIdx.x * blockDim.x + threadIdx.x;
    if (e < Ev) { rkv[e] = (unsigned short)atomicAdd(&cv[dv[e]], 1); return; }
    e -= Ev;
    if (e < Eh) { rkh[e] = (unsigned short)atomicAdd(&ch[dh[e]], 1); return; }
    e -= Eh;
    if (e < Ei) { rki[e] = (unsigned short)atomicAdd(&ci[di[e]], 1); return; }
    e -= Ei;
    if (e < Es) rks[e] = (unsigned short)atomicAdd(&cs[ds[e]], 1);
}

// batched per-256-block exclusive scan; also emits dinv=rsqrt(deg) for vv/ss
__global__ void k_scanb_all(const int* __restrict__ cv, const int* __restrict__ ch,
                            const int* __restrict__ ci, const int* __restrict__ cs,
                            int* __restrict__ rv, int* __restrict__ rh,
                            int* __restrict__ ri, int* __restrict__ rs,
                            float* __restrict__ dv, float* __restrict__ ds,
                            int* __restrict__ bsum, int nv, int ns, int nbv, int nbs) {
    __shared__ int sh[256];
    int blk = blockIdx.x;
    const int* cnt; int* rp; float* dinv; int n; int lb;
    if (blk < nbv)                { cnt = cv; rp = rv; dinv = dv;      n = nv; lb = blk; }
    else if (blk < nbv + nbs)     { cnt = ch; rp = rh; dinv = nullptr; n = ns; lb = blk - nbv; }
    else if (blk < nbv + 2 * nbs) { cnt = ci; rp = ri; dinv = nullptr; n = ns; lb = blk - nbv - nbs; }
    else                          { cnt = cs; rp = rs; dinv = ds;      n = ns; lb = blk - nbv - 2 * nbs; }
    int i = lb * 256 + threadIdx.x;
    int v = (i < n) ? cnt[i] : 0;
    if (dinv && i < n) dinv[i] = v > 0 ? rsqrtf((float)v) : 0.f;
    sh[threadIdx.x] = v; __syncthreads();
    for (int off = 1; off < 256; off <<= 1) {
        int t = (threadIdx.x >= off) ? sh[threadIdx.x - off] : 0;
        __syncthreads();
        sh[threadIdx.x] += t; __syncthreads();
    }
    if (i < n) rp[i] = sh[threadIdx.x] - v;
    if (threadIdx.x == 255) bsum[blk] = sh[255];
}

// segmented top scan: block g scans graph g's block sums in place
__global__ void k_scant_all(int* __restrict__ bsum, int nbv, int nbs) {
    __shared__ int sh[1024];
    int g = blockIdx.x;
    int off = (g == 0) ? 0 : nbv + (g - 1) * nbs;
    int nb  = (g == 0) ? nbv : nbs;
    int tid = threadIdx.x;
    int v = (tid < nb) ? bsum[off + tid] : 0;
    sh[tid] = v; __syncthreads();
    for (int o2 = 1; o2 < 1024; o2 <<= 1) {
        int t = (tid >= o2) ? sh[tid - o2] : 0;
        __syncthreads();
        sh[tid] += t; __syncthreads();
    }
    if (tid < nb) bsum[off + tid] = sh[tid] - v;
}

// finalize rowptrs (add block offsets), set rp[n]=E
__global__ void k_scana_all(int* __restrict__ rv, int* __restrict__ rh,
                            int* __restrict__ ri, int* __restrict__ rs,
                            const int* __restrict__ bsum, int nv, int ns, int nbv, int nbs,
                            int Ev, int Eh, int Ei, int Es) {
    int blk = blockIdx.x;
    int* rp; int n; int lb; int E;
    if (blk < nbv)                { rp = rv; n = nv; lb = blk;               E = Ev; }
    else if (blk < nbv + nbs)     { rp = rh; n = ns; lb = blk - nbv;         E = Eh; }
    else if (blk < nbv + 2 * nbs) { rp = ri; n = ns; lb = blk - nbv - nbs;   E = Ei; }
    else                          { rp = rs; n = ns; lb = blk - nbv - 2*nbs; E = Es; }
    int i = lb * 256 + threadIdx.x;
    if (i < n) rp[i] += bsum[blk];
    if (i == 0) rp[n] = E;
}

// atomic-free fills
__global__ void k_fill(const int* __restrict__ src, const int* __restrict__ dst,
                       const unsigned short* __restrict__ rk, const int* __restrict__ rowptr,
                       int* __restrict__ csr_src, int E) {
    int e = blockIdx.x * blockDim.x + threadIdx.x;
    if (e >= E) return;
    int p = rowptr[dst[e]] + rk[e];
    csr_src[p] = src[e];
}

__global__ void k_fill_w8(const int* __restrict__ src, const int* __restrict__ dst,
                          const float* __restrict__ w, const unsigned short* __restrict__ rk,
                          const int* __restrict__ rowptr, int2* __restrict__ csr_sw, int E) {
    int e = blockIdx.x * blockDim.x + threadIdx.x;
    if (e >= E) return;
    int p = rowptr[dst[e]] + rk[e];
    csr_sw[p] = make_int2(src[e], __float_as_int(w[e]));
}

// ================= gathers =================

__global__ void k_gather5(const float* __restrict__ x, const int* __restrict__ rowptr,
                          const int* __restrict__ csr_src, const float* __restrict__ dinv,
                          float* __restrict__ out, int n) {
    int d = blockIdx.x * blockDim.x + threadIdx.x;
    if (d >= n) return;
    int b = rowptr[d], e = rowptr[d + 1];
    float dd = dinv[d];
    float a0 = 0, a1 = 0, a2 = 0, a3 = 0, a4 = 0;
    int p = b;
    for (; p + 4 <= e; p += 4) {
        int s0 = csr_src[p], s1 = csr_src[p+1], s2 = csr_src[p+2], s3 = csr_src[p+3];
        const float* x0 = x + (size_t)s0 * 5;
        const float* x1 = x + (size_t)s1 * 5;
        const float* x2 = x + (size_t)s2 * 5;
        const float* x3 = x + (size_t)s3 * 5;
        float w0 = dd * dinv[s0], w1 = dd * dinv[s1], w2 = dd * dinv[s2], w3 = dd * dinv[s3];
        a0 += x0[0]*w0 + x1[0]*w1 + x2[0]*w2 + x3[0]*w3;
        a1 += x0[1]*w0 + x1[1]*w1 + x2[1]*w2 + x3[1]*w3;
        a2 += x0[2]*w0 + x1[2]*w1 + x2[2]*w2 + x3[2]*w3;
        a3 += x0[3]*w0 + x1[3]*w1 + x2[3]*w2 + x3[3]*w3;
        a4 += x0[4]*w0 + x1[4]*w1 + x2[4]*w2 + x3[4]*w3;
    }
    for (; p < e; p++) {
        int s = csr_src[p];
        float w = dd * dinv[s];
        const float* xp = x + (size_t)s * 5;
        a0 += xp[0]*w; a1 += xp[1]*w; a2 += xp[2]*w; a3 += xp[3]*w; a4 += xp[4]*w;
    }
    float* op = out + (size_t)d * 5;
    op[0] = a0; op[1] = a1; op[2] = a2; op[3] = a3; op[4] = a4;
}

// 64-channel gather: wave per dst row; 4 groups x 16 lanes x float4; 4-edge-deep MLP
// MODE: 0 = plain sum (csr_src), 1 = per-edge weight (int2 packed), 2 = gcn norm
template<int MODE>
__global__ void k_gather64(const float* __restrict__ x, const int* __restrict__ rowptr,
                           const int* __restrict__ csr_src, const int2* __restrict__ csr_sw,
                           const float* __restrict__ dinv, float* __restrict__ out, int n) {
    int wid = (int)(((long long)blockIdx.x * blockDim.x + threadIdx.x) >> 6);
    if (wid >= n) return;
    int lane = threadIdx.x & 63;
    int g = lane >> 4, q = lane & 15;
    int b = rowptr[wid], e = rowptr[wid + 1];
    float dd = (MODE == 2) ? dinv[wid] : 0.f;
    float4 acc = make_float4(0.f, 0.f, 0.f, 0.f);
    int p = b + g;
    // main: group g keeps rows p, p+4, p+8, p+12 in flight
    for (; p + 12 < e; p += 16) {
        int s0, s1, s2, s3;
        float w0 = 1.f, w1 = 1.f, w2 = 1.f, w3 = 1.f;
        if (MODE == 1) {
            int2 e0 = csr_sw[p], e1 = csr_sw[p+4], e2 = csr_sw[p+8], e3 = csr_sw[p+12];
            s0 = e0.x; w0 = __int_as_float(e0.y);
            s1 = e1.x; w1 = __int_as_float(e1.y);
            s2 = e2.x; w2 = __int_as_float(e2.y);
            s3 = e3.x; w3 = __int_as_float(e3.y);
        } else {
            s0 = csr_src[p]; s1 = csr_src[p+4]; s2 = csr_src[p+8]; s3 = csr_src[p+12];
            if (MODE == 2) {
                w0 = dd * dinv[s0]; w1 = dd * dinv[s1];
                w2 = dd * dinv[s2]; w3 = dd * dinv[s3];
            }
        }
        float4 v0 = ((const float4*)(x + (size_t)s0 * 64))[q];
        float4 v1 = ((const float4*)(x + (size_t)s1 * 64))[q];
        float4 v2 = ((const float4*)(x + (size_t)s2 * 64))[q];
        float4 v3 = ((const float4*)(x + (size_t)s3 * 64))[q];
        if (MODE == 0) {
            acc.x += v0.x + v1.x + v2.x + v3.x;
            acc.y += v0.y + v1.y + v2.y + v3.y;
            acc.z += v0.z + v1.z + v2.z + v3.z;
            acc.w += v0.w + v1.w + v2.w + v3.w;
        } else {
            acc.x += v0.x*w0 + v1.x*w1 + v2.x*w2 + v3.x*w3;
            acc.y += v0.y*w0 + v1.y*w1 + v2.y*w2 + v3.y*w3;
            acc.z += v0.z*w0 + v1.z*w1 + v2.z*w2 + v3.z*w3;
            acc.w += v0.w*w0 + v1.w*w1 + v2.w*w2 + v3.w*w3;
        }
    }
    // tail: stride-4 per group
    for (; p < e; p += 4) {
        int s; float w = 1.f;
        if (MODE == 1) { int2 e0 = csr_sw[p]; s = e0.x; w = __int_as_float(e0.y); }
        else { s = csr_src[p]; if (MODE == 2) w = dd * dinv[s]; }
        float4 v = ((const float4*)(x + (size_t)s * 64))[q];
        if (MODE == 0) { acc.x += v.x; acc.y += v.y; acc.z += v.z; acc.w += v.w; }
        else { acc.x += v.x*w; acc.y += v.y*w; acc.z += v.z*w; acc.w += v.w*w; }
    }
    #pragma unroll
    for (int off = 16; off < 64; off <<= 1) {
        acc.x += __shfl_xor(acc.x, off, 64);
        acc.y += __shfl_xor(acc.y, off, 64);
        acc.z += __shfl_xor(acc.z, off, 64);
        acc.w += __shfl_xor(acc.w, off, 64);
    }
    if (g == 0) ((float4*)(out + (size_t)wid * 64))[q] = acc;
}

// ================= dense combines (wave-tiled register GEMMs) =================

__global__ __launch_bounds__(256, 4)
void k_tag1_w(const float* __restrict__ x, const float* __restrict__ h1,
              const float* __restrict__ h2, const float* __restrict__ W,
              const float* __restrict__ b, float* __restrict__ out, int n) {
    int wv = (int)(((long long)blockIdx.x * blockDim.x + threadIdx.x) >> 6);
    int lane = threadIdx.x & 63;
    int i0 = wv * 4;
    if (i0 >= n) return;
    float v[4], acc[4];
    #pragma unroll
    for (int r = 0; r < 4; r++) {
        int i = (i0 + r < n) ? i0 + r : n - 1;
        float t = 0.f;
        if (lane < 5)                     t = x [(size_t)i * 5 + lane];
        else if (lane >= 8 && lane < 13)  t = h1[(size_t)i * 5 + lane - 8];
        else if (lane >= 16 && lane < 21) t = h2[(size_t)i * 5 + lane - 16];
        v[r] = t;
        acc[r] = b[lane];
    }
    #pragma unroll
    for (int m = 0; m < 3; m++) {
        #pragma unroll
        for (int k = 0; k < 5; k++) {
            float wk = W[(m * 5 + k) * 64 + lane];
            #pragma unroll
            for (int r = 0; r < 4; r++) acc[r] += bcast(v[r], m * 8 + k) * wk;
        }
    }
    #pragma unroll
    for (int r = 0; r < 4; r++)
        if (i0 + r < n) out[(size_t)(i0 + r) * 64 + lane] = fmaxf(acc[r], 0.f);
}

__global__ __launch_bounds__(256, 4)
void k_gc_w(const float* __restrict__ agg, const float* __restrict__ st,
            const float* __restrict__ Wrel, const float* __restrict__ Wroot,
            const float* __restrict__ b, float* __restrict__ out, int n) {
    int wv = (int)(((long long)blockIdx.x * blockDim.x + threadIdx.x) >> 6);
    int lane = threadIdx.x & 63;
    int i0 = wv * 4;
    if (i0 >= n) return;
    float xs[4], sr[4], acc[4];
    #pragma unroll
    for (int r = 0; r < 4; r++) {
        int i = (i0 + r < n) ? i0 + r : n - 1;
        xs[r] = agg[(size_t)i * 64 + lane];
        sr[r] = (lane < 6) ? st[(size_t)i * 6 + lane] : 0.f;
        acc[r] = b[lane];
    }
    #pragma unroll 8
    for (int k = 0; k < 64; k++) {
        float wk = Wrel[k * 64 + lane];
        #pragma unroll
        for (int r = 0; r < 4; r++) acc[r] += bcast(xs[r], k) * wk;
    }
    #pragma unroll
    for (int k = 0; k < 6; k++) {
        float wk = Wroot[k * 64 + lane];
        #pragma unroll
        for (int r = 0; r < 4; r++) acc[r] += bcast(sr[r], k) * wk;
    }
    #pragma unroll
    for (int r = 0; r < 4; r++)
        if (i0 + r < n) out[(size_t)(i0 + r) * 64 + lane] = fmaxf(acc[r], 0.f);
}

__global__ __launch_bounds__(256, 4)
void k_sage_w(const float* __restrict__ ssum, const int* __restrict__ rp,
              const float* __restrict__ sx, const float* __restrict__ Wl,
              const float* __restrict__ Wr, const float* __restrict__ bl,
              float* __restrict__ out, int n) {
    int wv = (int)(((long long)blockIdx.x * blockDim.x + threadIdx.x) >> 6);
    int lane = threadIdx.x & 63;
    int i0 = wv * 4;
    if (i0 >= n) return;
    float xs[4], ys[4], acc[4];
    #pragma unroll
    for (int r = 0; r < 4; r++) {
        int i = (i0 + r < n) ? i0 + r : n - 1;
        float cnt = (float)(rp[i + 1] - rp[i]);
        float rs = 1.f / fmaxf(cnt, 1.f);
        xs[r] = ssum[(size_t)i * 64 + lane] * rs;
        ys[r] = sx[(size_t)i * 64 + lane];
        acc[r] = bl[lane];
    }
    #pragma unroll 8
    for (int k = 0; k < 64; k++) {
        float wl = Wl[k * 64 + lane];
        float wr = Wr[k * 64 + lane];
        #pragma unroll
        for (int r = 0; r < 4; r++)
            acc[r] += bcast(xs[r], k) * wl + bcast(ys[r], k) * wr;
    }
    #pragma unroll
    for (int r = 0; r < 4; r++)
        if (i0 + r < n) out[(size_t)(i0 + r) * 64 + lane] = fmaxf(acc[r], 0.f);
}

template<bool INIT>
__global__ __launch_bounds__(256, 4)
void k_mm_w(const float* __restrict__ x, const float* __restrict__ W,
            const float* __restrict__ bias, float* __restrict__ out, int n) {
    int wv = (int)(((long long)blockIdx.x * blockDim.x + threadIdx.x) >> 6);
    int lane = threadIdx.x & 63;
    int i0 = wv * 4;
    if (i0 >= n) return;
    float xs[4], acc[4];
    #pragma unroll
    for (int r = 0; r < 4; r++) {
        int i = (i0 + r < n) ? i0 + r : n - 1;
        xs[r] = x[(size_t)i * 64 + lane];
        acc[r] = INIT ? bias[lane] : out[(size_t)i * 64 + lane];
    }
    #pragma unroll 8
    for (int k = 0; k < 64; k++) {
        float wk = W[k * 64 + lane];
        #pragma unroll
        for (int r = 0; r < 4; r++) acc[r] += bcast(xs[r], k) * wk;
    }
    #pragma unroll
    for (int r = 0; r < 4; r++)
        if (i0 + r < n) out[(size_t)(i0 + r) * 64 + lane] = acc[r];
}

__global__ void k_final(const float* __restrict__ x, const float* __restrict__ W,
                        const float* __restrict__ b, float* __restrict__ out, int n) {
    int t = blockIdx.x * blockDim.x + threadIdx.x;
    if (t >= n * 8) return;
    int i = t >> 3, o = t & 7;
    float acc = b[o];
    #pragma unroll 8
    for (int k = 0; k < 64; k++) acc += fmaxf(x[i * 64 + k], 0.f) * W[k * 8 + o];
    out[t] = acc;
}

static inline unsigned gblk(long long n) { return (unsigned)((n + BLK - 1) / BLK); }
static inline unsigned gwv4(long long n) { return gblk(((n + 3) / 4) * 64); }

extern "C" void kernel_launch(void* const* d_in, const int* in_sizes, int n_in,
                              void* d_out, int out_size, void* d_ws, size_t ws_size,
                              hipStream_t stream) {
    const float* game_x  = (const float*)d_in[0];
    const float* state_x = (const float*)d_in[1];
    const int*   ei_vv   = (const int*)d_in[2];
    const int*   ei_h    = (const int*)d_in[3];
    const float* ea_h    = (const float*)d_in[4];
    const int*   ei_in   = (const int*)d_in[5];
    const int*   ei_ss   = (const int*)d_in[6];
    const float* tag1_W  = (const float*)d_in[7];
    const float* tag1_b  = (const float*)d_in[8];
    const float* tag2_W  = (const float*)d_in[9];
    const float* tag2_b  = (const float*)d_in[10];
    const float* gc_Wrel = (const float*)d_in[11];
    const float* gc_b    = (const float*)d_in[12];
    const float* gc_Wroot= (const float*)d_in[13];
    const float* sage_Wl = (const float*)d_in[14];
    const float* sage_bl = (const float*)d_in[15];
    const float* sage_Wr = (const float*)d_in[16];
    const float* lin_W   = (const float*)d_in[17];
    const float* lin_b   = (const float*)d_in[18];

    const int NV  = in_sizes[0] / 5;
    const int NS  = in_sizes[1] / 6;
    const int EVV = in_sizes[2] / 2;
    const int EH  = in_sizes[3] / 2;
    const int EIN = in_sizes[5] / 2;
    const int ESS = in_sizes[6] / 2;

    const int *vv_s = ei_vv,  *vv_d = ei_vv + EVV;
    const int *h_s  = ei_h,   *h_d  = ei_h  + EH;
    const int *in_s = ei_in,  *in_d = ei_in + EIN;
    const int *ss_s = ei_ss,  *ss_d = ei_ss + ESS;

    // ---------------- workspace layout (4-byte words), ~80 MB ----------------
    float* wsf = (float*)d_ws;
    size_t o = 0;
    float* gx = wsf + o; o += (size_t)NV * 64;                    // gx | sx3
    float* B1 = wsf + o; o += (size_t)EIN + 64 + (size_t)NS * 64; // agg | insrc+ssum | hA
    float* B2 = wsf + o; o += (size_t)NS * 64;                    // sx | hB
    float* B4 = wsf + o; o += (size_t)NS * 64;                    // h1v+h2v | hsw | sx2
    int*   vs = (int*)(wsf + o); o += (size_t)(EVV > ESS ? EVV : ESS); // vvsrc | sssrc
    // per-edge ranks (ushort) — alive until each graph's fill
    unsigned short* rkv = (unsigned short*)(wsf + o);
    unsigned short* rkh = rkv + EVV;
    unsigned short* rki = rkh + EH;
    unsigned short* rks = rki + EIN;
    o += ((size_t)EVV + EH + EIN + ESS + 1) / 2;
    // CSR-skeleton pool
    int* cv = (int*)(wsf + o);
    int* ch = cv + NV;
    int* ci = ch + NS;
    int* cs = ci + NS;
    int* rv = cs + NS;            // NV+1
    int* rh = rv + NV + 1;        // NS+1
    int* ri = rh + NS + 1;        // NS+1
    int* rs = ri + NS + 1;        // NS+1
    float* dinv_v = (float*)(rs + NS + 1);  // NV
    float* dinv_s = dinv_v + NV;            // NS
    int* bsum = (int*)(dinv_s + NS);        // up to 1024

    float* ssum = B1 + (size_t)EIN + 64;

    // ================= Phase 0: batched CSR skeleton =================
    hipMemsetAsync(cv, 0, (size_t)(NV + 3 * NS) * sizeof(int), stream);
    long long Etot = (long long)EVV + EH + EIN + ESS;
    k_hist_all<<<gblk(Etot), BLK, 0, stream>>>(vv_d, h_d, in_d, ss_d, cv, ch, ci, cs,
                                               rkv, rkh, rki, rks, EVV, EH, EIN, ESS);
    int nbv = (NV + 255) / 256, nbs = (NS + 255) / 256;
    int NB = nbv + 3 * nbs;
    k_scanb_all<<<NB, 256, 0, stream>>>(cv, ch, ci, cs, rv, rh, ri, rs,
                                        dinv_v, dinv_s, bsum, NV, NS, nbv, nbs);
    k_scant_all<<<4, 1024, 0, stream>>>(bsum, nbv, nbs);
    k_scana_all<<<NB, 256, 0, stream>>>(rv, rh, ri, rs, bsum,
                                        NV, NS, nbv, nbs, EVV, EH, EIN, ESS);

    // ================= Stage A: TAGConv1 on v-v =================
    k_fill<<<gblk(EVV), BLK, 0, stream>>>(vv_s, vv_d, rkv, rv, vs, EVV);
    float* h1v = B4;
    float* h2v = B4 + (size_t)NV * 5;
    k_gather5<<<gblk(NV), BLK, 0, stream>>>(game_x, rv, vs, dinv_v, h1v, NV);
    k_gather5<<<gblk(NV), BLK, 0, stream>>>(h1v,    rv, vs, dinv_v, h2v, NV);
    k_tag1_w<<<gwv4(NV), BLK, 0, stream>>>(game_x, h1v, h2v, tag1_W, tag1_b, gx, NV);

    // ================= Stage B: GraphConv (weighted) =================
    int2* hsw = (int2*)B4;   // h1v/h2v dead
    k_fill_w8<<<gblk(EH), BLK, 0, stream>>>(h_s, h_d, ea_h, rkh, rh, hsw, EH);
    k_gather64<1><<<gblk((long long)NS * 64), BLK, 0, stream>>>(gx, rh, nullptr, hsw, nullptr, B1, NS);
    k_gc_w<<<gwv4(NS), BLK, 0, stream>>>(B1, state_x, gc_Wrel, gc_Wroot, gc_b, B2, NS);

    // ================= Stage C: SAGE mean =================
    int* insrc = (int*)B1;   // agg dead
    k_fill<<<gblk(EIN), BLK, 0, stream>>>(in_s, in_d, rki, ri, insrc, EIN);
    k_gather64<0><<<gblk((long long)NS * 64), BLK, 0, stream>>>(gx, ri, insrc, nullptr, nullptr, ssum, NS);
    float* sx2 = B4;         // hsw dead
    k_sage_w<<<gwv4(NS), BLK, 0, stream>>>(ssum, ri, B2, sage_Wl, sage_Wr, sage_bl, sx2, NS);

    // ================= Stage D: TAGConv2 on s-s (K=3) =================
    k_fill<<<gblk(ESS), BLK, 0, stream>>>(ss_s, ss_d, rks, rs, vs, ESS);  // vvsrc dead
    float* sx3 = gx;         // gx dead after stage-C gather
    float* hA  = B1;         // insrc+ssum dead after sage
    float* hB  = B2;         // sx dead after sage

    k_mm_w<true><<<gwv4(NS), BLK, 0, stream>>>(sx2, tag2_W, tag2_b, sx3, NS);
    k_gather64<2><<<gblk((long long)NS * 64), BLK, 0, stream>>>(sx2, rs, vs, nullptr, dinv_s, hA, NS);
    k_mm_w<false><<<gwv4(NS), BLK, 0, stream>>>(hA, tag2_W + 4096, nullptr, sx3, NS);
    k_gather64<2><<<gblk((long long)NS * 64), BLK, 0, stream>>>(hA, rs, vs, nullptr, dinv_s, hB, NS);
    k_mm_w<false><<<gwv4(NS), BLK, 0, stream>>>(hB, tag2_W + 8192, nullptr, sx3, NS);
    k_gather64<2><<<gblk((long long)NS * 64), BLK, 0, stream>>>(hB, rs, vs, nullptr, dinv_s, hA, NS);
    k_mm_w<false><<<gwv4(NS), BLK, 0, stream>>>(hA, tag2_W + 12288, nullptr, sx3, NS);

    // ================= Stage E: final linear (relu fused) =================
    k_final<<<gblk((long long)NS * 8), BLK, 0, stream>>>(sx3, lin_W, lin_b, (float*)d_out, NS);
}

// Round 8
// 631.721 us; speedup vs baseline: 3.3048x; 1.0540x over previous
//
#include <hip/hip_runtime.h>

#define BLK 256

// broadcast lane l of v across the wave (l wave-uniform; dynamic is legal)
__device__ __forceinline__ float bcast(float v, int l) {
    return __int_as_float(__builtin_amdgcn_readlane(__float_as_int(v), l));
}
// fp32 <-> bf16 (round-to-nearest-even)
__device__ __forceinline__ unsigned short f2bf(float f) {
    unsigned u = __float_as_uint(f);
    return (unsigned short)((u + 0x7FFFu + ((u >> 16) & 1u)) >> 16);
}
__device__ __forceinline__ float bf2f(unsigned short b) {
    return __uint_as_float(((unsigned)b) << 16);
}

// ================= batched CSR skeleton (all 4 graphs) =================
// hist returns each edge's rank within its dst (ushort, deg << 65536) so the
// fill kernel needs NO atomics: slot = rowptr[dst] + rank.

__global__ void k_hist_all(const int* __restrict__ dv, const int* __restrict__ dh,
                           const int* __restrict__ di, const int* __restrict__ ds,
                           int* __restrict__ cv, int* __restrict__ ch,
                           int* __restrict__ ci, int* __restrict__ cs,
                           unsigned short* __restrict__ rkv, unsigned short* __restrict__ rkh,
                           unsigned short* __restrict__ rki, unsigned short* __restrict__ rks,
                           int Ev, int Eh, int Ei, int Es) {
    int e = blockIdx.x * blockDim.x + threadIdx.x;
    if (e < Ev) { rkv[e] = (unsigned short)atomicAdd(&cv[dv[e]], 1); return; }
    e -= Ev;
    if (e < Eh) { rkh[e] = (unsigned short)atomicAdd(&ch[dh[e]], 1); return; }
    e -= Eh;
    if (e < Ei) { rki[e] = (unsigned short)atomicAdd(&ci[di[e]], 1); return; }
    e -= Ei;
    if (e < Es) rks[e] = (unsigned short)atomicAdd(&cs[ds[e]], 1);
}

// batched per-256-block exclusive scan; also emits dinv=rsqrt(deg) for vv/ss
__global__ void k_scanb_all(const int* __restrict__ cv, const int* __restrict__ ch,
                            const int* __restrict__ ci, const int* __restrict__ cs,
                            int* __restrict__ rv, int* __restrict__ rh,
                            int* __restrict__ ri, int* __restrict__ rs,
                            float* __restrict__ dv, float* __restrict__ ds,
                            int* __restrict__ bsum, int nv, int ns, int nbv, int nbs) {
    __shared__ int sh[256];
    int blk = blockIdx.x;
    const int* cnt; int* rp; float* dinv; int n; int lb;
    if (blk < nbv)                { cnt = cv; rp = rv; dinv = dv;      n = nv; lb = blk; }
    else if (blk < nbv + nbs)     { cnt = ch; rp = rh; dinv = nullptr; n = ns; lb = blk - nbv; }
    else if (blk < nbv + 2 * nbs) { cnt = ci; rp = ri; dinv = nullptr; n = ns; lb = blk - nbv - nbs; }
    else                          { cnt = cs; rp = rs; dinv = ds;      n = ns; lb = blk - nbv - 2 * nbs; }
    int i = lb * 256 + threadIdx.x;
    int v = (i < n) ? cnt[i] : 0;
    if (dinv && i < n) dinv[i] = v > 0 ? rsqrtf((float)v) : 0.f;
    sh[threadIdx.x] = v; __syncthreads();
    for (int off = 1; off < 256; off <<= 1) {
        int t = (threadIdx.x >= off) ? sh[threadIdx.x - off] : 0;
        __syncthreads();
        sh[threadIdx.x] += t; __syncthreads();
    }
    if (i < n) rp[i] = sh[threadIdx.x] - v;
    if (threadIdx.x == 255) bsum[blk] = sh[255];
}

__global__ void k_scant_all(int* __restrict__ bsum, int nbv, int nbs) {
    __shared__ int sh[1024];
    int g = blockIdx.x;
    int off = (g == 0) ? 0 : nbv + (g - 1) * nbs;
    int nb  = (g == 0) ? nbv : nbs;
    int tid = threadIdx.x;
    int v = (tid < nb) ? bsum[off + tid] : 0;
    sh[tid] = v; __syncthreads();
    for (int o2 = 1; o2 < 1024; o2 <<= 1) {
        int t = (tid >= o2) ? sh[tid - o2] : 0;
        __syncthreads();
        sh[tid] += t; __syncthreads();
    }
    if (tid < nb) bsum[off + tid] = sh[tid] - v;
}

__global__ void k_scana_all(int* __restrict__ rv, int* __restrict__ rh,
                            int* __restrict__ ri, int* __restrict__ rs,
                            const int* __restrict__ bsum, int nv, int ns, int nbv, int nbs,
                            int Ev, int Eh, int Ei, int Es) {
    int blk = blockIdx.x;
    int* rp; int n; int lb; int E;
    if (blk < nbv)                { rp = rv; n = nv; lb = blk;               E = Ev; }
    else if (blk < nbv + nbs)     { rp = rh; n = ns; lb = blk - nbv;         E = Eh; }
    else if (blk < nbv + 2 * nbs) { rp = ri; n = ns; lb = blk - nbv - nbs;   E = Ei; }
    else                          { rp = rs; n = ns; lb = blk - nbv - 2*nbs; E = Es; }
    int i = lb * 256 + threadIdx.x;
    if (i < n) rp[i] += bsum[blk];
    if (i == 0) rp[n] = E;
}

// one dispatch: atomic-free fill of all 4 CSRs
__global__ void k_fill_all(
    const int* __restrict__ vv_s, const int* __restrict__ vv_d,
    const unsigned short* __restrict__ rkv, const int* __restrict__ rv, int* __restrict__ vvsrc,
    const int* __restrict__ h_s, const int* __restrict__ h_d, const float* __restrict__ hw,
    const unsigned short* __restrict__ rkh, const int* __restrict__ rh, int2* __restrict__ hsw,
    const int* __restrict__ in_s, const int* __restrict__ in_d,
    const unsigned short* __restrict__ rki, const int* __restrict__ ri, int* __restrict__ insrc,
    const int* __restrict__ ss_s, const int* __restrict__ ss_d,
    const unsigned short* __restrict__ rks, const int* __restrict__ rs, int* __restrict__ sssrc,
    int Ev, int Eh, int Ei, int Es) {
    int e = blockIdx.x * blockDim.x + threadIdx.x;
    if (e < Ev) { vvsrc[rv[vv_d[e]] + rkv[e]] = vv_s[e]; return; }
    e -= Ev;
    if (e < Eh) { hsw[rh[h_d[e]] + rkh[e]] = make_int2(h_s[e], __float_as_int(hw[e])); return; }
    e -= Eh;
    if (e < Ei) { insrc[ri[in_d[e]] + rki[e]] = in_s[e]; return; }
    e -= Ei;
    if (e < Es) sssrc[rs[ss_d[e]] + rks[e]] = ss_s[e];
}

// ================= gathers =================

__global__ void k_gather5(const float* __restrict__ x, const int* __restrict__ rowptr,
                          const int* __restrict__ csr_src, const float* __restrict__ dinv,
                          float* __restrict__ out, int n) {
    int d = blockIdx.x * blockDim.x + threadIdx.x;
    if (d >= n) return;
    int b = rowptr[d], e = rowptr[d + 1];
    float dd = dinv[d];
    float a0 = 0, a1 = 0, a2 = 0, a3 = 0, a4 = 0;
    int p = b;
    for (; p + 4 <= e; p += 4) {
        int s0 = csr_src[p], s1 = csr_src[p+1], s2 = csr_src[p+2], s3 = csr_src[p+3];
        const float* x0 = x + (size_t)s0 * 5;
        const float* x1 = x + (size_t)s1 * 5;
        const float* x2 = x + (size_t)s2 * 5;
        const float* x3 = x + (size_t)s3 * 5;
        float w0 = dd * dinv[s0], w1 = dd * dinv[s1], w2 = dd * dinv[s2], w3 = dd * dinv[s3];
        a0 += x0[0]*w0 + x1[0]*w1 + x2[0]*w2 + x3[0]*w3;
        a1 += x0[1]*w0 + x1[1]*w1 + x2[1]*w2 + x3[1]*w3;
        a2 += x0[2]*w0 + x1[2]*w1 + x2[2]*w2 + x3[2]*w3;
        a3 += x0[3]*w0 + x1[3]*w1 + x2[3]*w2 + x3[3]*w3;
        a4 += x0[4]*w0 + x1[4]*w1 + x2[4]*w2 + x3[4]*w3;
    }
    for (; p < e; p++) {
        int s = csr_src[p];
        float w = dd * dinv[s];
        const float* xp = x + (size_t)s * 5;
        a0 += xp[0]*w; a1 += xp[1]*w; a2 += xp[2]*w; a3 += xp[3]*w; a4 += xp[4]*w;
    }
    float* op = out + (size_t)d * 5;
    op[0] = a0; op[1] = a1; op[2] = a2; op[3] = a3; op[4] = a4;
}

// 64-ch gather over bf16 rows: wave per dst row; 4 groups x 16 lanes x ushort4(8B);
// 4-edge-deep MLP; fp32 accumulate.
// MODE: 0 = plain sum, 1 = per-edge weight (int2 packed), 2 = symmetric gcn norm
// OUTBF: write bf16 row (for next gather hop) vs fp32 row
template<int MODE, bool OUTBF>
__global__ void k_gather64(const unsigned short* __restrict__ xbf, const int* __restrict__ rowptr,
                           const int* __restrict__ csr_src, const int2* __restrict__ csr_sw,
                           const float* __restrict__ dinv, void* __restrict__ outp, int n) {
    int wid = (int)(((long long)blockIdx.x * blockDim.x + threadIdx.x) >> 6);
    if (wid >= n) return;
    int lane = threadIdx.x & 63;
    int g = lane >> 4, q = lane & 15;
    int b = rowptr[wid], e = rowptr[wid + 1];
    float dd = (MODE == 2) ? dinv[wid] : 0.f;
    float4 acc = make_float4(0.f, 0.f, 0.f, 0.f);
    int p = b + g;
    for (; p + 12 < e; p += 16) {
        int s0, s1, s2, s3;
        float w0 = 1.f, w1 = 1.f, w2 = 1.f, w3 = 1.f;
        if (MODE == 1) {
            int2 e0 = csr_sw[p], e1 = csr_sw[p+4], e2 = csr_sw[p+8], e3 = csr_sw[p+12];
            s0 = e0.x; w0 = __int_as_float(e0.y);
            s1 = e1.x; w1 = __int_as_float(e1.y);
            s2 = e2.x; w2 = __int_as_float(e2.y);
            s3 = e3.x; w3 = __int_as_float(e3.y);
        } else {
            s0 = csr_src[p]; s1 = csr_src[p+4]; s2 = csr_src[p+8]; s3 = csr_src[p+12];
            if (MODE == 2) {
                w0 = dd * dinv[s0]; w1 = dd * dinv[s1];
                w2 = dd * dinv[s2]; w3 = dd * dinv[s3];
            }
        }
        ushort4 u0 = ((const ushort4*)(xbf + (size_t)s0 * 64))[q];
        ushort4 u1 = ((const ushort4*)(xbf + (size_t)s1 * 64))[q];
        ushort4 u2 = ((const ushort4*)(xbf + (size_t)s2 * 64))[q];
        ushort4 u3 = ((const ushort4*)(xbf + (size_t)s3 * 64))[q];
        acc.x += bf2f(u0.x)*w0 + bf2f(u1.x)*w1 + bf2f(u2.x)*w2 + bf2f(u3.x)*w3;
        acc.y += bf2f(u0.y)*w0 + bf2f(u1.y)*w1 + bf2f(u2.y)*w2 + bf2f(u3.y)*w3;
        acc.z += bf2f(u0.z)*w0 + bf2f(u1.z)*w1 + bf2f(u2.z)*w2 + bf2f(u3.z)*w3;
        acc.w += bf2f(u0.w)*w0 + bf2f(u1.w)*w1 + bf2f(u2.w)*w2 + bf2f(u3.w)*w3;
    }
    for (; p < e; p += 4) {
        int s; float w = 1.f;
        if (MODE == 1) { int2 e0 = csr_sw[p]; s = e0.x; w = __int_as_float(e0.y); }
        else { s = csr_src[p]; if (MODE == 2) w = dd * dinv[s]; }
        ushort4 u = ((const ushort4*)(xbf + (size_t)s * 64))[q];
        acc.x += bf2f(u.x)*w; acc.y += bf2f(u.y)*w;
        acc.z += bf2f(u.z)*w; acc.w += bf2f(u.w)*w;
    }
    #pragma unroll
    for (int off = 16; off < 64; off <<= 1) {
        acc.x += __shfl_xor(acc.x, off, 64);
        acc.y += __shfl_xor(acc.y, off, 64);
        acc.z += __shfl_xor(acc.z, off, 64);
        acc.w += __shfl_xor(acc.w, off, 64);
    }
    if (g == 0) {
        if (OUTBF) {
            ushort4 ov;
            ov.x = f2bf(acc.x); ov.y = f2bf(acc.y); ov.z = f2bf(acc.z); ov.w = f2bf(acc.w);
            ((ushort4*)outp)[(size_t)wid * 16 + q] = ov;
        } else {
            ((float4*)outp)[(size_t)wid * 16 + q] = acc;
        }
    }
}

// ================= dense combines (wave-tiled register GEMMs) =================

// gx_bf = bf16(relu(b + x@W0 + h1@W1 + h2@W2))
__global__ __launch_bounds__(256, 4)
void k_tag1_w(const float* __restrict__ x, const float* __restrict__ h1,
              const float* __restrict__ h2, const float* __restrict__ W,
              const float* __restrict__ b, unsigned short* __restrict__ out, int n) {
    int wv = (int)(((long long)blockIdx.x * blockDim.x + threadIdx.x) >> 6);
    int lane = threadIdx.x & 63;
    int i0 = wv * 4;
    if (i0 >= n) return;
    float v[4], acc[4];
    #pragma unroll
    for (int r = 0; r < 4; r++) {
        int i = (i0 + r < n) ? i0 + r : n - 1;
        float t = 0.f;
        if (lane < 5)                     t = x [(size_t)i * 5 + lane];
        else if (lane >= 8 && lane < 13)  t = h1[(size_t)i * 5 + lane - 8];
        else if (lane >= 16 && lane < 21) t = h2[(size_t)i * 5 + lane - 16];
        v[r] = t;
        acc[r] = b[lane];
    }
    #pragma unroll
    for (int m = 0; m < 3; m++) {
        #pragma unroll
        for (int k = 0; k < 5; k++) {
            float wk = W[(m * 5 + k) * 64 + lane];
            #pragma unroll
            for (int r = 0; r < 4; r++) acc[r] += bcast(v[r], m * 8 + k) * wk;
        }
    }
    #pragma unroll
    for (int r = 0; r < 4; r++)
        if (i0 + r < n) out[(size_t)(i0 + r) * 64 + lane] = f2bf(fmaxf(acc[r], 0.f));
}

// sx = relu(b + agg@Wrel + state@Wroot)   (fp32 out; only read by dense sage)
__global__ __launch_bounds__(256, 4)
void k_gc_w(const float* __restrict__ agg, const float* __restrict__ st,
            const float* __restrict__ Wrel, const float* __restrict__ Wroot,
            const float* __restrict__ b, float* __restrict__ out, int n) {
    int wv = (int)(((long long)blockIdx.x * blockDim.x + threadIdx.x) >> 6);
    int lane = threadIdx.x & 63;
    int i0 = wv * 4;
    if (i0 >= n) return;
    float xs[4], sr[4], acc[4];
    #pragma unroll
    for (int r = 0; r < 4; r++) {
        int i = (i0 + r < n) ? i0 + r : n - 1;
        xs[r] = agg[(size_t)i * 64 + lane];
        sr[r] = (lane < 6) ? st[(size_t)i * 6 + lane] : 0.f;
        acc[r] = b[lane];
    }
    #pragma unroll 8
    for (int k = 0; k < 64; k++) {
        float wk = Wrel[k * 64 + lane];
        #pragma unroll
        for (int r = 0; r < 4; r++) acc[r] += bcast(xs[r], k) * wk;
    }
    #pragma unroll
    for (int k = 0; k < 6; k++) {
        float wk = Wroot[k * 64 + lane];
        #pragma unroll
        for (int r = 0; r < 4; r++) acc[r] += bcast(sr[r], k) * wk;
    }
    #pragma unroll
    for (int r = 0; r < 4; r++)
        if (i0 + r < n) out[(size_t)(i0 + r) * 64 + lane] = fmaxf(acc[r], 0.f);
}

// sx2_bf = bf16(relu(bl + (ssum/max(cnt,1))@Wl + sx@Wr))
__global__ __launch_bounds__(256, 4)
void k_sage_w(const float* __restrict__ ssum, const int* __restrict__ rp,
              const float* __restrict__ sx, const float* __restrict__ Wl,
              const float* __restrict__ Wr, const float* __restrict__ bl,
              unsigned short* __restrict__ out, int n) {
    int wv = (int)(((long long)blockIdx.x * blockDim.x + threadIdx.x) >> 6);
    int lane = threadIdx.x & 63;
    int i0 = wv * 4;
    if (i0 >= n) return;
    float xs[4], ys[4], acc[4];
    #pragma unroll
    for (int r = 0; r < 4; r++) {
        int i = (i0 + r < n) ? i0 + r : n - 1;
        float cnt = (float)(rp[i + 1] - rp[i]);
        float rs = 1.f / fmaxf(cnt, 1.f);
        xs[r] = ssum[(size_t)i * 64 + lane] * rs;
        ys[r] = sx[(size_t)i * 64 + lane];
        acc[r] = bl[lane];
    }
    #pragma unroll 8
    for (int k = 0; k < 64; k++) {
        float wl = Wl[k * 64 + lane];
        float wr = Wr[k * 64 + lane];
        #pragma unroll
        for (int r = 0; r < 4; r++)
            acc[r] += bcast(xs[r], k) * wl + bcast(ys[r], k) * wr;
    }
    #pragma unroll
    for (int r = 0; r < 4; r++)
        if (i0 + r < n) out[(size_t)(i0 + r) * 64 + lane] = f2bf(fmaxf(acc[r], 0.f));
}

// INIT: out = bias + x@W ; else: out += x@W   (x rows bf16, W 64x64 fp32, out fp32)
template<bool INIT>
__global__ __launch_bounds__(256, 4)
void k_mm_w(const unsigned short* __restrict__ xbf, const float* __restrict__ W,
            const float* __restrict__ bias, float* __restrict__ out, int n) {
    int wv = (int)(((long long)blockIdx.x * blockDim.x + threadIdx.x) >> 6);
    int lane = threadIdx.x & 63;
    int i0 = wv * 4;
    if (i0 >= n) return;
    float xs[4], acc[4];
    #pragma unroll
    for (int r = 0; r < 4; r++) {
        int i = (i0 + r < n) ? i0 + r : n - 1;
        xs[r] = bf2f(xbf[(size_t)i * 64 + lane]);
        acc[r] = INIT ? bias[lane] : out[(size_t)i * 64 + lane];
    }
    #pragma unroll 8
    for (int k = 0; k < 64; k++) {
        float wk = W[k * 64 + lane];
        #pragma unroll
        for (int r = 0; r < 4; r++) acc[r] += bcast(xs[r], k) * wk;
    }
    #pragma unroll
    for (int r = 0; r < 4; r++)
        if (i0 + r < n) out[(size_t)(i0 + r) * 64 + lane] = acc[r];
}

__global__ void k_final(const float* __restrict__ x, const float* __restrict__ W,
                        const float* __restrict__ b, float* __restrict__ out, int n) {
    int t = blockIdx.x * blockDim.x + threadIdx.x;
    if (t >= n * 8) return;
    int i = t >> 3, o = t & 7;
    float acc = b[o];
    #pragma unroll 8
    for (int k = 0; k < 64; k++) acc += fmaxf(x[i * 64 + k], 0.f) * W[k * 8 + o];
    out[t] = acc;
}

static inline unsigned gblk(long long n) { return (unsigned)((n + BLK - 1) / BLK); }
static inline unsigned gwv4(long long n) { return gblk(((n + 3) / 4) * 64); }

extern "C" void kernel_launch(void* const* d_in, const int* in_sizes, int n_in,
                              void* d_out, int out_size, void* d_ws, size_t ws_size,
                              hipStream_t stream) {
    const float* game_x  = (const float*)d_in[0];
    const float* state_x = (const float*)d_in[1];
    const int*   ei_vv   = (const int*)d_in[2];
    const int*   ei_h    = (const int*)d_in[3];
    const float* ea_h    = (const float*)d_in[4];
    const int*   ei_in   = (const int*)d_in[5];
    const int*   ei_ss   = (const int*)d_in[6];
    const float* tag1_W  = (const float*)d_in[7];
    const float* tag1_b  = (const float*)d_in[8];
    const float* tag2_W  = (const float*)d_in[9];
    const float* tag2_b  = (const float*)d_in[10];
    const float* gc_Wrel = (const float*)d_in[11];
    const float* gc_b    = (const float*)d_in[12];
    const float* gc_Wroot= (const float*)d_in[13];
    const float* sage_Wl = (const float*)d_in[14];
    const float* sage_bl = (const float*)d_in[15];
    const float* sage_Wr = (const float*)d_in[16];
    const float* lin_W   = (const float*)d_in[17];
    const float* lin_b   = (const float*)d_in[18];

    const int NV  = in_sizes[0] / 5;
    const int NS  = in_sizes[1] / 6;
    const int EVV = in_sizes[2] / 2;
    const int EH  = in_sizes[3] / 2;
    const int EIN = in_sizes[5] / 2;
    const int ESS = in_sizes[6] / 2;

    const int *vv_s = ei_vv,  *vv_d = ei_vv + EVV;
    const int *h_s  = ei_h,   *h_d  = ei_h  + EH;
    const int *in_s = ei_in,  *in_d = ei_in + EIN;
    const int *ss_s = ei_ss,  *ss_d = ei_ss + ESS;

    // ---------------- workspace layout (4-byte words), ~72 MB ----------------
    float* wsf = (float*)d_ws;
    size_t o = 0;
    unsigned short* gx_bf = (unsigned short*)(wsf + o);   // NV x 64 bf16
    float* sx3 = wsf + o; o += (size_t)NV * 32;           // alias (NS*64 fp32 == NV*32 words)
    float* B1 = wsf + o; o += (size_t)NS * 64;            // agg | ssum | hA_bf
    float* B2 = wsf + o; o += (size_t)NS * 64;            // sx | hB_bf
    float* B4 = wsf + o; o += (size_t)NS * 32;            // h1v+h2v (NV*10) | sx2_bf (NS*32)
    int*  vvsrc = (int*)(wsf + o); o += (size_t)EVV;
    int*  sssrc = (int*)(wsf + o); o += (size_t)ESS;
    int*  insrc = (int*)(wsf + o); o += (size_t)EIN;
    int2* hsw   = (int2*)(wsf + o); o += (size_t)EH * 2;
    unsigned short* rkv = (unsigned short*)(wsf + o);
    unsigned short* rkh = rkv + EVV;
    unsigned short* rki = rkh + EH;
    unsigned short* rks = rki + EIN;
    o += ((size_t)EVV + EH + EIN + ESS + 1) / 2;
    int* cv = (int*)(wsf + o);
    int* ch = cv + NV;
    int* ci = ch + NS;
    int* cs = ci + NS;
    int* rv = cs + NS;            // NV+1
    int* rh = rv + NV + 1;        // NS+1
    int* ri = rh + NS + 1;        // NS+1
    int* rs = ri + NS + 1;        // NS+1
    float* dinv_v = (float*)(rs + NS + 1);  // NV
    float* dinv_s = dinv_v + NV;            // NS
    int* bsum = (int*)(dinv_s + NS);        // up to 1024

    unsigned short* hA_bf  = (unsigned short*)B1;
    unsigned short* hB_bf  = (unsigned short*)B2;
    unsigned short* sx2_bf = (unsigned short*)B4;

    // ================= Phase 0: batched CSR build =================
    hipMemsetAsync(cv, 0, (size_t)(NV + 3 * NS) * sizeof(int), stream);
    long long Etot = (long long)EVV + EH + EIN + ESS;
    k_hist_all<<<gblk(Etot), BLK, 0, stream>>>(vv_d, h_d, in_d, ss_d, cv, ch, ci, cs,
                                               rkv, rkh, rki, rks, EVV, EH, EIN, ESS);
    int nbv = (NV + 255) / 256, nbs = (NS + 255) / 256;
    int NB = nbv + 3 * nbs;
    k_scanb_all<<<NB, 256, 0, stream>>>(cv, ch, ci, cs, rv, rh, ri, rs,
                                        dinv_v, dinv_s, bsum, NV, NS, nbv, nbs);
    k_scant_all<<<4, 1024, 0, stream>>>(bsum, nbv, nbs);
    k_scana_all<<<NB, 256, 0, stream>>>(rv, rh, ri, rs, bsum,
                                        NV, NS, nbv, nbs, EVV, EH, EIN, ESS);
    k_fill_all<<<gblk(Etot), BLK, 0, stream>>>(
        vv_s, vv_d, rkv, rv, vvsrc,
        h_s, h_d, ea_h, rkh, rh, hsw,
        in_s, in_d, rki, ri, insrc,
        ss_s, ss_d, rks, rs, sssrc,
        EVV, EH, EIN, ESS);

    // ================= Stage A: TAGConv1 on v-v =================
    float* h1v = B4;
    float* h2v = B4 + (size_t)NV * 5;
    k_gather5<<<gblk(NV), BLK, 0, stream>>>(game_x, rv, vvsrc, dinv_v, h1v, NV);
    k_gather5<<<gblk(NV), BLK, 0, stream>>>(h1v,    rv, vvsrc, dinv_v, h2v, NV);
    k_tag1_w<<<gwv4(NV), BLK, 0, stream>>>(game_x, h1v, h2v, tag1_W, tag1_b, gx_bf, NV);

    // ================= Stage B: GraphConv (weighted) =================
    k_gather64<1, false><<<gblk((long long)NS * 64), BLK, 0, stream>>>(gx_bf, rh, nullptr, hsw, nullptr, B1, NS);
    k_gc_w<<<gwv4(NS), BLK, 0, stream>>>(B1, state_x, gc_Wrel, gc_Wroot, gc_b, B2, NS);

    // ================= Stage C: SAGE mean =================
    k_gather64<0, false><<<gblk((long long)NS * 64), BLK, 0, stream>>>(gx_bf, ri, insrc, nullptr, nullptr, B1, NS);
    k_sage_w<<<gwv4(NS), BLK, 0, stream>>>(B1, ri, B2, sage_Wl, sage_Wr, sage_bl, sx2_bf, NS);

    // ================= Stage D: TAGConv2 on s-s (K=3) =================
    // gx_bf dead -> sx3 alias; B1 (ssum) dead -> hA_bf; B2 (sx) dead -> hB_bf
    k_mm_w<true><<<gwv4(NS), BLK, 0, stream>>>(sx2_bf, tag2_W, tag2_b, sx3, NS);
    k_gather64<2, true><<<gblk((long long)NS * 64), BLK, 0, stream>>>(sx2_bf, rs, sssrc, nullptr, dinv_s, hA_bf, NS);
    k_mm_w<false><<<gwv4(NS), BLK, 0, stream>>>(hA_bf, tag2_W + 4096, nullptr, sx3, NS);
    k_gather64<2, true><<<gblk((long long)NS * 64), BLK, 0, stream>>>(hA_bf, rs, sssrc, nullptr, dinv_s, hB_bf, NS);
    k_mm_w<false><<<gwv4(NS), BLK, 0, stream>>>(hB_bf, tag2_W + 8192, nullptr, sx3, NS);
    k_gather64<2, true><<<gblk((long long)NS * 64), BLK, 0, stream>>>(hB_bf, rs, sssrc, nullptr, dinv_s, hA_bf, NS);
    k_mm_w<false><<<gwv4(NS), BLK, 0, stream>>>(hA_bf, tag2_W + 12288, nullptr, sx3, NS);

    // ================= Stage E: final linear (relu fused) =================
    k_final<<<gblk((long long)NS * 8), BLK, 0, stream>>>(sx3, lin_W, lin_b, (float*)d_out, NS);
}